// Round 4
// baseline (5859.650 us; speedup 1.0000x reference)
//
#include <hip/hip_runtime.h>
#include <math.h>

constexpr int cNS = 64, cNV = 32, cNB = 8, cL = 4, cEMB = 32, cNT = 10;
constexpr float PI_F = 3.14159265358979323846f;
constexpr float INV_SQRT_NN = 0.17677669529663687f;   // 1/sqrt(32)
constexpr float BESSEL_C = 2.3094010767585034f;       // sqrt(2/3)*sqrt(8)
constexpr float SQRT3 = 1.7320508075688772f;

typedef __attribute__((ext_vector_type(2))) float f32x2;
typedef __attribute__((ext_vector_type(4))) float f32x4;

__device__ __forceinline__ f32x2 pkfma(f32x2 a, f32x2 b, f32x2 c) {
  f32x2 d;
  asm("v_pk_fma_f32 %0, %1, %2, %3" : "=v"(d) : "v"(a), "v"(b), "v"(c));
  return d;
}

// sum across the 4 consecutive lanes of an edge-group (DPP quad_perm, VALU pipe)
__device__ __forceinline__ float quadsum(float v) {
  v += __int_as_float(__builtin_amdgcn_update_dpp(0, __float_as_int(v), 0xB1, 0xF, 0xF, true));
  v += __int_as_float(__builtin_amdgcn_update_dpp(0, __float_as_int(v), 0x4E, 0xF, 0xF, true));
  return v;
}

// ---------------- precompute kernels ----------------

__global__ void k_precompA(const float* __restrict__ emb, const float* __restrict__ Wss,
                           float* __restrict__ A) {
  int idx = blockIdx.x * 256 + threadIdx.x;
  if (idx >= cL * cNT * 64 * 96) return;
  int m = idx % 96;
  int u = (idx / 96) % 64;
  int t = (idx / (96 * 64)) % cNT;
  int l = idx / (96 * 64 * cNT);
  float acc = 0.f;
#pragma unroll
  for (int e = 0; e < 32; ++e)
    acc += emb[t * 32 + e] * Wss[((size_t)(l * 64 + u) * 32 + e) * 96 + m];
  A[idx] = acc;
}

__global__ void k_precompB(const float* __restrict__ emb, const float* __restrict__ Wsv_,
                           float* __restrict__ B) {
  int idx = blockIdx.x * 256 + threadIdx.x;
  if (idx >= cL * cNT * 32 * 32) return;
  int vo = idx % 32;
  int u = (idx / 32) % 32;
  int t = (idx / 1024) % cNT;
  int l = idx / (1024 * cNT);
  float acc = 0.f;
#pragma unroll
  for (int e = 0; e < 32; ++e)
    acc += emb[t * 32 + e] * Wsv_[((size_t)(l * 32 + u) * 32 + e) * 32 + vo];
  B[idx] = acc;
}

__global__ void k_transpose_fc(const float* __restrict__ fc1, const float* __restrict__ fc2,
                               float* __restrict__ fc1T, float* __restrict__ fc2T) {
  int idx = blockIdx.x * 256 + threadIdx.x;
  if (idx < cL * 12288) {
    int l = idx / 12288, p = idx % 12288;
    int o = p / 64, j = p % 64;
    fc2T[idx] = fc2[l * 12288 + j * 192 + o];
  }
  if (idx < cL * 1024) {
    int l = idx / 1024, p = idx % 1024;
    int j = p / 16, t = p % 16;
    fc1T[idx] = fc1[l * 1024 + t * 64 + j];
  }
}

__global__ void k_init(const float* __restrict__ x, const float* __restrict__ Wup,
                       float* __restrict__ v, float* __restrict__ v_old,
                       float* __restrict__ xcur, int N) {
  int idx = blockIdx.x * 256 + threadIdx.x;
  if (idx >= N * 32) return;
  int n = idx >> 5, vc = idx & 31;
  float w0 = Wup[vc], w1 = Wup[32 + vc];
#pragma unroll
  for (int c = 0; c < 3; ++c) {
    float val = x[n * 6 + c] * w0 + x[n * 6 + 3 + c] * w1;
    v[idx * 3 + c] = val;
    v_old[idx * 3 + c] = val;
  }
  if (vc < 6) xcur[n * 6 + vc] = x[n * 6 + vc];
}

// ---------------- CSR build ----------------

__global__ void k_zero_i(int* __restrict__ p, int n) {
  int i = blockIdx.x * 256 + threadIdx.x;
  if (i < n) p[i] = 0;
}

__global__ void k_hist(const int* __restrict__ edst, int* __restrict__ deg, int E) {
  int e = blockIdx.x * 256 + threadIdx.x;
  if (e < E) atomicAdd(&deg[edst[e]], 1);
}

__global__ __launch_bounds__(1024) void k_scan(const int* __restrict__ deg,
                                               int* __restrict__ row_ptr,
                                               int* __restrict__ cursor, int N) {
  __shared__ int part[1024];
  int t = threadIdx.x;
  int chunk = (N + 1023) / 1024;
  int base = t * chunk;
  int sum = 0;
  for (int i = 0; i < chunk; ++i) {
    int idx = base + i;
    if (idx < N) sum += deg[idx];
  }
  part[t] = sum;
  __syncthreads();
  for (int off = 1; off < 1024; off <<= 1) {
    int val = (t >= off) ? part[t - off] : 0;
    __syncthreads();
    part[t] += val;
    __syncthreads();
  }
  int run = (t > 0) ? part[t - 1] : 0;
  for (int i = 0; i < chunk; ++i) {
    int idx = base + i;
    if (idx < N) {
      row_ptr[idx] = run;
      cursor[idx] = run;
      run += deg[idx];
    }
  }
  if (t == 1023) row_ptr[N] = part[1023];
}

__global__ void k_scatter(const int* __restrict__ edst, int* __restrict__ cursor,
                          int* __restrict__ pos_of_e, int E) {
  int e = blockIdx.x * 256 + threadIdx.x;
  if (e < E) pos_of_e[e] = atomicAdd(&cursor[edst[e]], 1);
}

// ---------------- edge kernel: 4 lanes per edge, pk_fma + DPP quad reduce --------
// row layout (stride 192): [0..95]=msg_s, [96..191]=msg_v (m*3+c). SZERO: stride 96.
template <bool SZERO>
__global__ __launch_bounds__(256, 4) void k_edge_q(
    const float* __restrict__ xcur, const float* __restrict__ s, const float* __restrict__ v,
    const int* __restrict__ esrc, const int* __restrict__ pos_of_e,
    const float* __restrict__ fc1T, const float* __restrict__ b1,
    const float* __restrict__ fc2T, const float* __restrict__ Wsv,
    const float* __restrict__ Wvs, float* __restrict__ msgbuf, int E) {
  int tid = blockIdx.x * 256 + threadIdx.x;
  int e = tid >> 2, r = tid & 3;
  if (e >= E) return;
  int src = esrc[e];
  float* row = msgbuf + (size_t)pos_of_e[e] * (SZERO ? 96 : 192);

  // ---- geometry (duplicated across the 4 lanes; cheap)
  float fbuf[16];
  float a00, a01, a02, a10, a11, a12;
  {
    const float2* ps = (const float2*)(xcur + (size_t)src * 6);
    int dummy_dst;  // need dst coords: reload via pos? No: dst comes from edge list
    (void)dummy_dst;
  }
  // we need both endpoints' coords:
  {
    // esrc gave src; dst must be read too (geometry uses x[src]-x[dst])
  }
  // NOTE: dst index needed; load it:
  // (kept out of the struct-ish block above for clarity)
  {
  }
  // actual geometry:
  {
    // load dst index from the companion array passed via pos_of_e? no — separate param needed.
  }
  // --- real code below (dst passed separately) ---
  a00 = a01 = a02 = a10 = a11 = a12 = 0.f;  // overwritten
  (void)fbuf;
  // placeholder removed in k_edge_q2; this kernel is not used.
}

// Clean implementation with dst parameter.
template <bool SZERO>
__global__ __launch_bounds__(256, 4) void k_edge4(
    const float* __restrict__ xcur, const float* __restrict__ s, const float* __restrict__ v,
    const int* __restrict__ esrc, const int* __restrict__ edst,
    const int* __restrict__ pos_of_e,
    const float* __restrict__ fc1T, const float* __restrict__ b1,
    const float* __restrict__ fc2T, const float* __restrict__ Wsv,
    const float* __restrict__ Wvs, float* __restrict__ msgbuf, int E) {
  int tid = blockIdx.x * 256 + threadIdx.x;
  int e = tid >> 2, r = tid & 3;
  if (e >= E) return;
  int src = esrc[e], dst = edst[e];
  float* row = msgbuf + (size_t)pos_of_e[e] * (SZERO ? 96 : 192);

  float fbuf[16];
  float a00, a01, a02, a10, a11, a12;
  {
    const float2* ps = (const float2*)(xcur + (size_t)src * 6);
    const float2* pd = (const float2*)(xcur + (size_t)dst * 6);
    float2 A0 = ps[0], A1 = ps[1], A2 = ps[2];
    float2 B0 = pd[0], B1 = pd[1], B2 = pd[2];
    float xs[6] = {A0.x, A0.y, A1.x, A1.y, A2.x, A2.y};
    float xd[6] = {B0.x, B0.y, B1.x, B1.y, B2.x, B2.y};
#pragma unroll
    for (int i = 0; i < 2; ++i) {
      float vx = xs[3 * i + 0] - xd[3 * i + 0];
      float vy = xs[3 * i + 1] - xd[3 * i + 1];
      float vz = xs[3 * i + 2] - xd[3 * i + 2];
      float r2 = vx * vx + vy * vy + vz * vz;
      float rr = sqrtf(r2);
      float invr = 1.0f / rr;
      float th = (PI_F / 3.0f) * rr;
      float s1, c1;
      __sincosf(th, &s1, &c1);
      float twc = 2.0f * c1;
      float snm = 0.f, sn = s1;
      float fc = BESSEL_C * invr;
#pragma unroll
      for (int nn = 0; nn < 8; ++nn) {
        fbuf[8 * i + nn] = fc * sn;
        float nx = twc * sn - snm;
        snm = sn;
        sn = nx;
      }
      float uu = (2.0f / 3.0f) * rr - 2.0f;
      float cut;
      if (uu > 0.f) cut = 0.f;
      else if (uu < -1.f) cut = 1.f;
      else cut = (1.0f - __cosf(PI_F * uu)) * 0.5f;
      float sc = cut * SQRT3 * invr;
      if (i == 0) { a00 = vx * sc; a01 = vy * sc; a02 = vz * sc; }
      else        { a10 = vx * sc; a11 = vy * sc; a12 = vz * sc; }
    }
  }
  f32x2 f2[8];
#pragma unroll
  for (int i = 0; i < 8; ++i) { f2[i].x = fbuf[2 * i]; f2[i].y = fbuf[2 * i + 1]; }

  // ---- hid chunk: lane r owns j in [16r, 16r+16)
  const float* fct = fc1T + r * 256;   // 16 rows x 16
  const float* b1p = b1 + r * 16;
  f32x2 hid2[8];
#pragma unroll
  for (int jj = 0; jj < 16; ++jj) {
    const f32x4* rw = (const f32x4*)(fct + jj * 16);
    f32x4 w0 = rw[0], w1 = rw[1], w2 = rw[2], w3 = rw[3];
    f32x2 p = {0.f, 0.f};
    p = pkfma(f2[0], w0.xy, p); p = pkfma(f2[1], w0.zw, p);
    p = pkfma(f2[2], w1.xy, p); p = pkfma(f2[3], w1.zw, p);
    p = pkfma(f2[4], w2.xy, p); p = pkfma(f2[5], w2.zw, p);
    p = pkfma(f2[6], w3.xy, p); p = pkfma(f2[7], w3.zw, p);
    float acc = b1p[jj] + p.x + p.y;
    float hv = acc * (1.0f / (1.0f + __expf(-acc)));
    if (jj & 1) hid2[jj >> 1].y = hv; else hid2[jj >> 1].x = hv;
  }

  // ---- Pass A: q (lane r owns m in [8r, 8r+8)); msg_v -> row[96..191]
  if (!SZERO) {
    f32x2 q0[4], q1[4];
#pragma unroll
    for (int i = 0; i < 4; ++i) { q0[i] = f32x2{0.f, 0.f}; q1[i] = f32x2{0.f, 0.f}; }
    const float* srowp = s + (size_t)src * 64;
#pragma unroll 1
    for (int ub = 0; ub < 16; ++ub) {
      f32x4 s4 = *(const f32x4*)(srowp + ub * 4);
#pragma unroll
      for (int uu = 0; uu < 4; ++uu) {
        int u = ub * 4 + uu;
        float su = (uu == 0) ? s4.x : (uu == 1) ? s4.y : (uu == 2) ? s4.z : s4.w;
        const f32x4* cA = (const f32x4*)(fc2T + (size_t)(2 * u) * 64 + r * 16);
        const f32x4* cB = cA + 16;   // col 2u+1
        f32x2 p0 = {0.f, 0.f}, p1 = {0.f, 0.f};
#pragma unroll
        for (int ii = 0; ii < 4; ++ii) {
          f32x4 A = cA[ii], B = cB[ii];
          p0 = pkfma(hid2[2 * ii], A.xy, p0);
          p0 = pkfma(hid2[2 * ii + 1], A.zw, p0);
          p1 = pkfma(hid2[2 * ii], B.xy, p1);
          p1 = pkfma(hid2[2 * ii + 1], B.zw, p1);
        }
        float w10 = quadsum(p0.x + p0.y);
        float w11 = quadsum(p1.x + p1.y);
        float t0 = su * w10, t1 = su * w11;
        f32x2 t02 = {t0, t0}, t12 = {t1, t1};
        const f32x4* Wa4 = (const f32x4*)(Wsv + (size_t)u * 64 + 8 * r);
        const f32x4* Wb4 = Wa4 + 8;   // +32 floats (k=1)
        f32x4 WA0 = Wa4[0], WA1 = Wa4[1], WB0 = Wb4[0], WB1 = Wb4[1];
        q0[0] = pkfma(t02, WA0.xy, q0[0]); q0[1] = pkfma(t02, WA0.zw, q0[1]);
        q0[2] = pkfma(t02, WA1.xy, q0[2]); q0[3] = pkfma(t02, WA1.zw, q0[3]);
        q1[0] = pkfma(t12, WB0.xy, q1[0]); q1[1] = pkfma(t12, WB0.zw, q1[1]);
        q1[2] = pkfma(t12, WB1.xy, q1[2]); q1[3] = pkfma(t12, WB1.zw, q1[3]);
      }
    }
    float vmv[24];
#pragma unroll
    for (int i = 0; i < 4; ++i) {
      float Q0a = q0[i].x, Q0b = q0[i].y, Q1a = q1[i].x, Q1b = q1[i].y;
      vmv[6 * i + 0] = Q0a * a00 + Q1a * a10;
      vmv[6 * i + 1] = Q0a * a01 + Q1a * a11;
      vmv[6 * i + 2] = Q0a * a02 + Q1a * a12;
      vmv[6 * i + 3] = Q0b * a00 + Q1b * a10;
      vmv[6 * i + 4] = Q0b * a01 + Q1b * a11;
      vmv[6 * i + 5] = Q0b * a02 + Q1b * a12;
    }
    f32x4* outv = (f32x4*)(row + 96 + 24 * r);
#pragma unroll
    for (int i = 0; i < 6; ++i) {
      f32x4 t;
      t.x = vmv[4 * i + 0]; t.y = vmv[4 * i + 1];
      t.z = vmv[4 * i + 2]; t.w = vmv[4 * i + 3];
      outv[i] = t;
    }
  }

  // ---- Pass B: msg_s (lane r owns m in [24r, 24r+24)) -> row[0..95]
  f32x2 m2[12];
#pragma unroll
  for (int i = 0; i < 12; ++i) m2[i] = f32x2{0.f, 0.f};
  const float* vrowp = v + (size_t)src * 96;
#pragma unroll 1
  for (int ub = 0; ub < 8; ++ub) {
    const f32x4* vb = (const f32x4*)(vrowp + ub * 12);
    f32x4 vA = vb[0], vB = vb[1], vC = vb[2];
    float vl[12] = {vA.x, vA.y, vA.z, vA.w, vB.x, vB.y, vB.z, vB.w, vC.x, vC.y, vC.z, vC.w};
#pragma unroll
    for (int uu = 0; uu < 4; ++uu) {
      int u = ub * 4 + uu;
      float vx = vl[3 * uu + 0], vy = vl[3 * uu + 1], vz = vl[3 * uu + 2];
      float d0 = vx * a00 + vy * a01 + vz * a02;
      float d1 = vx * a10 + vy * a11 + vz * a12;
      const f32x4* cA = (const f32x4*)(fc2T + (size_t)(128 + 2 * u) * 64 + r * 16);
      const f32x4* cB = cA + 16;
      f32x2 p0 = {0.f, 0.f}, p1 = {0.f, 0.f};
#pragma unroll
      for (int ii = 0; ii < 4; ++ii) {
        f32x4 A = cA[ii], B = cB[ii];
        p0 = pkfma(hid2[2 * ii], A.xy, p0);
        p0 = pkfma(hid2[2 * ii + 1], A.zw, p0);
        p1 = pkfma(hid2[2 * ii], B.xy, p1);
        p1 = pkfma(hid2[2 * ii + 1], B.zw, p1);
      }
      float w20 = quadsum(p0.x + p0.y);
      float w21 = quadsum(p1.x + p1.y);
      float g0 = d0 * w20, g1 = d1 * w21;
      f32x2 g02 = {g0, g0}, g12 = {g1, g1};
      const f32x4* WA4 = (const f32x4*)(Wvs + (size_t)u * 192 + 24 * r);
      const f32x4* WB4 = WA4 + 24;   // +96 floats (k=1)
#pragma unroll
      for (int ii = 0; ii < 6; ++ii) {
        f32x4 A = WA4[ii];
        m2[2 * ii]     = pkfma(g02, A.xy, m2[2 * ii]);
        m2[2 * ii + 1] = pkfma(g02, A.zw, m2[2 * ii + 1]);
      }
#pragma unroll
      for (int ii = 0; ii < 6; ++ii) {
        f32x4 B = WB4[ii];
        m2[2 * ii]     = pkfma(g12, B.xy, m2[2 * ii]);
        m2[2 * ii + 1] = pkfma(g12, B.zw, m2[2 * ii + 1]);
      }
    }
  }
  f32x4* outs = (f32x4*)(row + 24 * r);
#pragma unroll
  for (int i = 0; i < 6; ++i) {
    f32x4 t;
    t.x = m2[2 * i].x; t.y = m2[2 * i].y;
    t.z = m2[2 * i + 1].x; t.w = m2[2 * i + 1].y;
    outs[i] = t;
  }
}

// ---------------- fused gather + node update (block of 128 per node) ----------------
template <bool SZERO>
__global__ __launch_bounds__(128) void k_gnode(
    const float* __restrict__ msg, const int* __restrict__ row_ptr,
    float* __restrict__ s, float* __restrict__ sold, float* __restrict__ v,
    float* __restrict__ vold,
    const float* __restrict__ Amat, const float* __restrict__ Bmat,
    const float* __restrict__ Ws, const float* __restrict__ Wv,
    const float* __restrict__ Wproj, const int* __restrict__ nattr,
    const float* __restrict__ hArr, const float* __restrict__ mixArr, int layer,
    float* __restrict__ xout, int N) {
  int n = blockIdx.x;
  int t = threadIdx.x;
  __shared__ float agg[192];
  __shared__ float srow[64];
  __shared__ float vrow[96];
  __shared__ float gateS[32];
  __shared__ float vnewS[96];
  int start = row_ptr[n], end = row_ptr[n + 1];
  if (SZERO) {
    if (t < 96) {
      float a0 = 0.f;
      for (int p = start; p < end; ++p) a0 += msg[(size_t)p * 96 + t];
      agg[t] = a0 * INV_SQRT_NN;
      agg[96 + t] = 0.f;
    }
  } else {
    float a0 = 0.f, a1 = 0.f;
    for (int p = start; p < end; ++p) {
      const float* rr = msg + (size_t)p * 192;
      a0 += rr[t];
      if (t < 64) a1 += rr[128 + t];
    }
    agg[t] = a0 * INV_SQRT_NN;
    if (t < 64) agg[128 + t] = a1 * INV_SQRT_NN;
  }
  if (t < 64) srow[t] = s[(size_t)n * 64 + t];
  if (t < 96) vrow[t] = v[(size_t)n * 96 + t];
  __syncthreads();
  int type = nattr[n];
  float hv = hArr[layer];
  float h2 = hv * hv;
  float mx = mixArr[layer];
  float cs = 0.f;
  if (t < 96) {
    cs = agg[t];
    const float* Ac = Amat + (size_t)type * 64 * 96 + t;
#pragma unroll 8
    for (int u = 0; u < 64; ++u) cs += srow[u] * Ac[u * 96];
  }
  if (t >= 64 && t < 96) gateS[t - 64] = 1.0f / (1.0f + __expf(-cs));
  __syncthreads();
  if (t < 64) {
    float gs = cs * (1.0f / (1.0f + __expf(-cs)));
    float sis = 0.f;
#pragma unroll 8
    for (int u = 0; u < 64; ++u) sis += srow[u] * Ws[u * 64 + t];
    float scur = srow[t];
    float sprev = sold[(size_t)n * 64 + t];
    float snew = 2.f * scur - sprev + h2 * (mx * gs + (mx - 1.f) * sis);
    sold[(size_t)n * 64 + t] = scur;
    s[(size_t)n * 64 + t] = snew;
  }
  if (t < 96) {
    int vch = t / 3, c = t - vch * 3;
    float cv = agg[96 + t];
    const float* Bc = Bmat + (size_t)type * 1024 + vch;
    float scv = 0.f, siv = 0.f;
#pragma unroll 8
    for (int u = 0; u < 32; ++u) {
      float vu = vrow[u * 3 + c];
      scv += vu * Bc[u * 32];
      siv += vu * Wv[u * 32 + vch];
    }
    cv += scv;
    float gv = cv * gateS[vch];
    float vcur = vrow[t];
    float vprev = vold[(size_t)n * 96 + t];
    float vnew = 2.f * vcur - vprev + h2 * (mx * gv + (mx - 1.f) * siv);
    vold[(size_t)n * 96 + t] = vcur;
    v[(size_t)n * 96 + t] = vnew;
    vnewS[t] = vnew;
  }
  __syncthreads();
  if (t < 6) {
    int i = t / 3, c = t - i * 3;
    float acc = 0.f;
#pragma unroll
    for (int vo = 0; vo < 32; ++vo) acc += vnewS[vo * 3 + c] * Wproj[vo * 2 + i];
    xout[(size_t)n * 6 + t] = acc;
  }
}

extern "C" void kernel_launch(void* const* d_in, const int* in_sizes, int n_in,
                              void* d_out, int out_size, void* d_ws, size_t ws_size,
                              hipStream_t stream) {
  const float* x = (const float*)d_in[0];
  const float* emb = (const float*)d_in[1];
  const float* Wup = (const float*)d_in[2];
  const float* Wproj = (const float*)d_in[3];
  const float* fc1 = (const float*)d_in[4];
  const float* b1 = (const float*)d_in[5];
  const float* fc2 = (const float*)d_in[6];
  const float* Wsv = (const float*)d_in[7];
  const float* Wvs = (const float*)d_in[8];
  const float* Wscs = (const float*)d_in[9];
  const float* Wscv = (const float*)d_in[10];
  const float* Ws = (const float*)d_in[11];
  const float* Wv = (const float*)d_in[12];
  const float* hArr = (const float*)d_in[13];
  const float* mixArr = (const float*)d_in[14];
  const int* nattr = (const int*)d_in[15];
  const int* esrc = (const int*)d_in[16];
  const int* edst = (const int*)d_in[17];

  const int N = in_sizes[0] / 6;
  const int E = in_sizes[16];

  float* ws = (float*)d_ws;
  size_t off = 0;
  auto alloc = [&](size_t nf) {
    float* p = ws + off;
    off += (nf + 3) & ~(size_t)3;
    return p;
  };
  float* sbuf = alloc((size_t)N * 64);
  float* sold = alloc((size_t)N * 64);
  float* vbuf = alloc((size_t)N * 96);
  float* vold = alloc((size_t)N * 96);
  float* xcur = alloc((size_t)N * 6);
  float* Amat = alloc((size_t)cL * cNT * 64 * 96);
  float* Bmat = alloc((size_t)cL * cNT * 32 * 32);
  float* fc2T = alloc((size_t)cL * 12288);
  float* fc1T = alloc((size_t)cL * 1024);
  size_t base_off = off;

  int* deg = (int*)(ws + base_off);
  int* row_ptr = deg + (N + 4);
  int* cursor = row_ptr + (N + 4);
  int* pos_of_e = cursor + (N + 4);
  size_t msg_off = base_off + ((size_t)(3 * (N + 4) + E + 3) & ~(size_t)3);
  float* msgbuf = ws + msg_off;

  hipMemsetAsync(sbuf, 0, sizeof(float) * (size_t)N * 128, stream);
  k_init<<<(N * 32 + 255) / 256, 256, 0, stream>>>(x, Wup, vbuf, vold, xcur, N);
  k_precompA<<<(cL * cNT * 64 * 96 + 255) / 256, 256, 0, stream>>>(emb, Wscs, Amat);
  k_precompB<<<(cL * cNT * 32 * 32 + 255) / 256, 256, 0, stream>>>(emb, Wscv, Bmat);
  k_transpose_fc<<<(cL * 12288 + 255) / 256, 256, 0, stream>>>(fc1, fc2, fc1T, fc2T);

  k_zero_i<<<(N + 255) / 256, 256, 0, stream>>>(deg, N);
  k_hist<<<(E + 255) / 256, 256, 0, stream>>>(edst, deg, E);
  k_scan<<<1, 1024, 0, stream>>>(deg, row_ptr, cursor, N);
  k_scatter<<<(E + 255) / 256, 256, 0, stream>>>(edst, cursor, pos_of_e, E);

  int eblocks = (E * 4 + 255) / 256;
  for (int l = 0; l < cL; ++l) {
    if (l == 0)
      k_edge4<true><<<eblocks, 256, 0, stream>>>(
          xcur, sbuf, vbuf, esrc, edst, pos_of_e, fc1T + l * 1024, b1 + l * 64,
          fc2T + l * 12288, Wsv + l * 4096, Wvs + l * 6144, msgbuf, E);
    else
      k_edge4<false><<<eblocks, 256, 0, stream>>>(
          xcur, sbuf, vbuf, esrc, edst, pos_of_e, fc1T + l * 1024, b1 + l * 64,
          fc2T + l * 12288, Wsv + l * 4096, Wvs + l * 6144, msgbuf, E);
    float* xout = (l == cL - 1) ? (float*)d_out : xcur;
    if (l == 0)
      k_gnode<true><<<N, 128, 0, stream>>>(
          msgbuf, row_ptr, sbuf, sold, vbuf, vold, Amat + (size_t)l * cNT * 64 * 96,
          Bmat + (size_t)l * cNT * 1024, Ws + l * 4096, Wv + l * 1024, Wproj, nattr,
          hArr, mixArr, l, xout, N);
    else
      k_gnode<false><<<N, 128, 0, stream>>>(
          msgbuf, row_ptr, sbuf, sold, vbuf, vold, Amat + (size_t)l * cNT * 64 * 96,
          Bmat + (size_t)l * cNT * 1024, Ws + l * 4096, Wv + l * 1024, Wproj, nattr,
          hArr, mixArr, l, xout, N);
  }
}

// Round 5
// 746.830 us; speedup vs baseline: 7.8460x; 7.8460x over previous
//
#include <hip/hip_runtime.h>
#include <math.h>

constexpr int cNS = 64, cNV = 32, cNB = 8, cL = 4, cEMB = 32, cNT = 10;
constexpr float PI_F = 3.14159265358979323846f;
constexpr float INV_SQRT_NN = 0.17677669529663687f;   // 1/sqrt(32)
constexpr float BESSEL_C = 2.3094010767585034f;       // sqrt(2/3)*sqrt(8)
constexpr float SQRT3 = 1.7320508075688772f;

typedef unsigned short u16;
typedef unsigned int u32;
typedef __attribute__((ext_vector_type(8))) short bf16x8;
typedef __attribute__((ext_vector_type(4))) float f32x4;
typedef __attribute__((ext_vector_type(2))) float f32x2;

__device__ __forceinline__ u16 f2b(float x) {   // f32 -> bf16 RNE
  u32 u = __float_as_uint(x);
  return (u16)((u + 0x7fffu + ((u >> 16) & 1u)) >> 16);
}
__device__ __forceinline__ float b2f(u16 h) { return __uint_as_float(((u32)h) << 16); }

__device__ __forceinline__ f32x4 mfma16(bf16x8 a, bf16x8 b, f32x4 c) {
  return __builtin_amdgcn_mfma_f32_16x16x32_bf16(a, b, c, 0, 0, 0);
}

// ---------------- precompute kernels ----------------

__global__ void k_precompA(const float* __restrict__ emb, const float* __restrict__ Wss,
                           float* __restrict__ A) {
  int idx = blockIdx.x * 256 + threadIdx.x;
  if (idx >= cL * cNT * 64 * 96) return;
  int m = idx % 96;
  int u = (idx / 96) % 64;
  int t = (idx / (96 * 64)) % cNT;
  int l = idx / (96 * 64 * cNT);
  float acc = 0.f;
#pragma unroll
  for (int e = 0; e < 32; ++e)
    acc += emb[t * 32 + e] * Wss[((size_t)(l * 64 + u) * 32 + e) * 96 + m];
  A[idx] = acc;
}

__global__ void k_precompB(const float* __restrict__ emb, const float* __restrict__ Wsv_,
                           float* __restrict__ B) {
  int idx = blockIdx.x * 256 + threadIdx.x;
  if (idx >= cL * cNT * 32 * 32) return;
  int vo = idx % 32;
  int u = (idx / 32) % 32;
  int t = (idx / 1024) % cNT;
  int l = idx / (1024 * cNT);
  float acc = 0.f;
#pragma unroll
  for (int e = 0; e < 32; ++e)
    acc += emb[t * 32 + e] * Wsv_[((size_t)(l * 32 + u) * 32 + e) * 32 + vo];
  B[idx] = acc;
}

// fc1T[l][j][t] = fc1[l][t][j]
__global__ void k_tr_fc1(const float* __restrict__ fc1, float* __restrict__ fc1T) {
  int idx = blockIdx.x * 256 + threadIdx.x;
  if (idx >= cL * 1024) return;
  int l = idx / 1024, p = idx % 1024;
  int j = p / 16, t = p % 16;
  fc1T[idx] = fc1[l * 1024 + t * 64 + j];
}

// pack fc2 / W_sv / W_vs into bf16 MFMA-B layouts:
// BL[(k/8)*N*8 + n*8 + (k%8)]
__global__ void k_packB(const float* __restrict__ fc2, const float* __restrict__ Wsv,
                        const float* __restrict__ Wvs, u16* __restrict__ fc2L,
                        u16* __restrict__ WsvL, u16* __restrict__ WvsL) {
  int idx = blockIdx.x * 256 + threadIdx.x;
  const int T1 = cL * 12288, T2 = cL * 2 * 2048, T3 = cL * 2 * 3072;
  if (idx < T1) {
    int l = idx / 12288, r = idx % 12288;
    int ki = r & 7, tt = r >> 3;
    int nn = tt % 192, kq = tt / 192;
    fc2L[idx] = f2b(fc2[((size_t)(l * 64) + kq * 8 + ki) * 192 + nn]);
  } else if (idx < T1 + T2) {
    int r0 = idx - T1;
    int l = r0 / 4096, r1 = r0 % 4096;
    int k2 = r1 / 2048, r = r1 % 2048;
    int ki = r & 7, tt = r >> 3;
    int mm = tt % 32, kq = tt / 32;
    WsvL[r0] = f2b(Wsv[((size_t)((l * 64 + kq * 8 + ki) * 2) + k2) * 32 + mm]);
  } else if (idx < T1 + T2 + T3) {
    int r0 = idx - T1 - T2;
    int l = r0 / 6144, r1 = r0 % 6144;
    int k2 = r1 / 3072, r = r1 % 3072;
    int ki = r & 7, tt = r >> 3;
    int mm = tt % 96, kq = tt / 96;
    WvsL[r0] = f2b(Wvs[((size_t)((l * 32 + kq * 8 + ki) * 2) + k2) * 96 + mm]);
  }
}

__global__ void k_init(const float* __restrict__ x, const float* __restrict__ Wup,
                       float* __restrict__ v, float* __restrict__ v_old,
                       float* __restrict__ xcur, int N) {
  int idx = blockIdx.x * 256 + threadIdx.x;
  if (idx >= N * 32) return;
  int n = idx >> 5, vc = idx & 31;
  float w0 = Wup[vc], w1 = Wup[32 + vc];
#pragma unroll
  for (int c = 0; c < 3; ++c) {
    float val = x[n * 6 + c] * w0 + x[n * 6 + 3 + c] * w1;
    v[idx * 3 + c] = val;
    v_old[idx * 3 + c] = val;
  }
  if (vc < 6) xcur[n * 6 + vc] = x[n * 6 + vc];
}

// ---------------- CSR build ----------------

__global__ void k_zero_i(int* __restrict__ p, int n) {
  int i = blockIdx.x * 256 + threadIdx.x;
  if (i < n) p[i] = 0;
}

__global__ void k_hist(const int* __restrict__ edst, int* __restrict__ deg, int E) {
  int e = blockIdx.x * 256 + threadIdx.x;
  if (e < E) atomicAdd(&deg[edst[e]], 1);
}

__global__ __launch_bounds__(1024) void k_scan(const int* __restrict__ deg,
                                               int* __restrict__ row_ptr,
                                               int* __restrict__ cursor, int N) {
  __shared__ int part[1024];
  int t = threadIdx.x;
  int chunk = (N + 1023) / 1024;
  int base = t * chunk;
  int sum = 0;
  for (int i = 0; i < chunk; ++i) {
    int idx = base + i;
    if (idx < N) sum += deg[idx];
  }
  part[t] = sum;
  __syncthreads();
  for (int off = 1; off < 1024; off <<= 1) {
    int val = (t >= off) ? part[t - off] : 0;
    __syncthreads();
    part[t] += val;
    __syncthreads();
  }
  int run = (t > 0) ? part[t - 1] : 0;
  for (int i = 0; i < chunk; ++i) {
    int idx = base + i;
    if (idx < N) {
      row_ptr[idx] = run;
      cursor[idx] = run;
      run += deg[idx];
    }
  }
  if (t == 1023) row_ptr[N] = part[1023];
}

__global__ void k_scatter(const int* __restrict__ edst, int* __restrict__ cursor,
                          int* __restrict__ pos_of_e, int E) {
  int e = blockIdx.x * 256 + threadIdx.x;
  if (e < E) pos_of_e[e] = atomicAdd(&cursor[edst[e]], 1);
}

// ---------------- per-edge geometry + small MLP (fp32) ----------------
// outputs: hidb [E][64] bf16, aE [E][8] f32 = {a00,a01,a02,a10,a11,a12,0,0}
__global__ __launch_bounds__(256) void k_geom(
    const float* __restrict__ xcur, const int* __restrict__ esrc, const int* __restrict__ edst,
    const float* __restrict__ fc1T, const float* __restrict__ b1,
    u16* __restrict__ hidb, float* __restrict__ aE, int E) {
  int e = blockIdx.x * 256 + threadIdx.x;
  if (e >= E) return;
  int src = esrc[e], dst = edst[e];

  float xs[6], xd[6];
  {
    const float2* ps = (const float2*)(xcur + (size_t)src * 6);
    const float2* pd = (const float2*)(xcur + (size_t)dst * 6);
    float2 A0 = ps[0], A1 = ps[1], A2 = ps[2];
    float2 B0 = pd[0], B1 = pd[1], B2 = pd[2];
    xs[0] = A0.x; xs[1] = A0.y; xs[2] = A1.x; xs[3] = A1.y; xs[4] = A2.x; xs[5] = A2.y;
    xd[0] = B0.x; xd[1] = B0.y; xd[2] = B1.x; xd[3] = B1.y; xd[4] = B2.x; xd[5] = B2.y;
  }

  float f[16], av[6];
#pragma unroll
  for (int i = 0; i < 2; ++i) {
    float vx = xs[3 * i + 0] - xd[3 * i + 0];
    float vy = xs[3 * i + 1] - xd[3 * i + 1];
    float vz = xs[3 * i + 2] - xd[3 * i + 2];
    float r2 = vx * vx + vy * vy + vz * vz;
    float rr = sqrtf(r2);
    float invr = 1.0f / rr;
    float th = (PI_F / 3.0f) * rr;
    float s1, c1;
    __sincosf(th, &s1, &c1);
    float twc = 2.0f * c1;
    float snm = 0.f, sn = s1;
    float fc = BESSEL_C * invr;
#pragma unroll
    for (int nn = 0; nn < 8; ++nn) {
      f[8 * i + nn] = fc * sn;
      float nx = twc * sn - snm;
      snm = sn;
      sn = nx;
    }
    float uu = (2.0f / 3.0f) * rr - 2.0f;
    float cut;
    if (uu > 0.f) cut = 0.f;
    else if (uu < -1.f) cut = 1.f;
    else cut = (1.0f - __cosf(PI_F * uu)) * 0.5f;
    float sc = cut * SQRT3 * invr;
    av[3 * i + 0] = vx * sc; av[3 * i + 1] = vy * sc; av[3 * i + 2] = vz * sc;
  }
  {
    f32x4 A1v = {av[0], av[1], av[2], av[3]};
    f32x4 A2v = {av[4], av[5], 0.f, 0.f};
    *(f32x4*)(aE + (size_t)e * 8) = A1v;
    *(f32x4*)(aE + (size_t)e * 8 + 4) = A2v;
  }

  u32 hb[32];
#pragma unroll 4
  for (int j = 0; j < 64; j += 2) {
    const f32x4* r0 = (const f32x4*)(fc1T + j * 16);
    const f32x4* r1 = (const f32x4*)(fc1T + (j + 1) * 16);
    float acc0 = b1[j], acc1 = b1[j + 1];
#pragma unroll
    for (int c4 = 0; c4 < 4; ++c4) {
      f32x4 w0 = r0[c4], w1 = r1[c4];
      acc0 += f[4 * c4] * w0[0] + f[4 * c4 + 1] * w0[1] + f[4 * c4 + 2] * w0[2] + f[4 * c4 + 3] * w0[3];
      acc1 += f[4 * c4] * w1[0] + f[4 * c4 + 1] * w1[1] + f[4 * c4 + 2] * w1[2] + f[4 * c4 + 3] * w1[3];
    }
    float h0 = acc0 * (1.0f / (1.0f + __expf(-acc0)));
    float h1 = acc1 * (1.0f / (1.0f + __expf(-acc1)));
    hb[j >> 1] = (u32)f2b(h0) | ((u32)f2b(h1) << 16);
  }
  u32* dst4 = (u32*)(hidb + (size_t)e * 64);
#pragma unroll
  for (int i = 0; i < 32; ++i) dst4[i] = hb[i];
}

// ---------------- MFMA edge kernel: wave = 16 edges ----------------
// msg row (bf16, stride 192): [0..95] msg_s[m], [96..191] msg_v at 96 + c*32 + m'
template <bool SZERO>
__global__ __launch_bounds__(256) void k_edge_mfma(
    const u16* __restrict__ hidb, const float* __restrict__ aE,
    const float* __restrict__ s, const float* __restrict__ v,
    const int* __restrict__ esrc, const int* __restrict__ pos_of_e,
    const u16* __restrict__ fc2L, const u16* __restrict__ WsvL0,
    const u16* __restrict__ WsvL1, const u16* __restrict__ WvsL0,
    const u16* __restrict__ WvsL1, u16* __restrict__ msgbuf, int E) {
  __shared__ u16 lwAll[4][16 * 200];   // per-wave [16 rows][200] bf16 (192 used)
  int wid = threadIdx.x >> 6, lane = threadIdx.x & 63;
  int gw = blockIdx.x * 4 + wid;
  int e0 = gw * 16;
  if (e0 >= E) return;
  u16* wb = lwAll[wid];
  int lrow = lane & 15, lg = lane >> 4;
  int erow = e0 + lrow;
  if (erow >= E) erow = E - 1;

  // ---- GEMM2: w[16,192] = hid[16,64] @ fc2[64,192], store bf16 to LDS permuted
  bf16x8 ha = *(const bf16x8*)(hidb + (size_t)erow * 64 + lg * 8);
  bf16x8 hbf = *(const bf16x8*)(hidb + (size_t)erow * 64 + 32 + lg * 8);
#pragma unroll
  for (int nb = (SZERO ? 8 : 0); nb < 12; ++nb) {
    bf16x8 b0 = *(const bf16x8*)(fc2L + (size_t)(lg * 192 + nb * 16 + lrow) * 8);
    bf16x8 b1v = *(const bf16x8*)(fc2L + (size_t)((4 + lg) * 192 + nb * 16 + lrow) * 8);
    f32x4 c = {0.f, 0.f, 0.f, 0.f};
    c = mfma16(ha, b0, c);
    c = mfma16(hbf, b1v, c);
    int n = nb * 16 + lrow;
    int pn = (n < 128) ? ((n & 1) * 64 + (n >> 1)) : (128 + (n & 1) * 32 + ((n - 128) >> 1));
    int rbase = 4 * lg * 200 + pn;
    wb[rbase] = f2b(c[0]);
    wb[rbase + 200] = f2b(c[1]);
    wb[rbase + 400] = f2b(c[2]);
    wb[rbase + 600] = f2b(c[3]);
  }
  asm volatile("s_waitcnt lgkmcnt(0)" ::: "memory");

  int src = esrc[erow];
  const u16* wrow = wb + lrow * 200;

  // ---- Q path: T_k = s_src (.) w1_k ; Q_k = T_k @ W_sv_k   ([16,64]x[64,32])
  f32x4 q0[2], q1[2];
  if (!SZERO) {
    const float* sp = s + (size_t)src * 64;
    float sv0[8], sv1[8];
    *(f32x4*)(sv0) = *(const f32x4*)(sp + lg * 8);
    *(f32x4*)(sv0 + 4) = *(const f32x4*)(sp + lg * 8 + 4);
    *(f32x4*)(sv1) = *(const f32x4*)(sp + 32 + lg * 8);
    *(f32x4*)(sv1 + 4) = *(const f32x4*)(sp + 32 + lg * 8 + 4);
    bf16x8 w0a = *(const bf16x8*)(wrow + lg * 8);
    bf16x8 w0b = *(const bf16x8*)(wrow + 32 + lg * 8);
    bf16x8 w1a = *(const bf16x8*)(wrow + 64 + lg * 8);
    bf16x8 w1b = *(const bf16x8*)(wrow + 96 + lg * 8);
    bf16x8 t0a, t0b, t1a, t1b;
#pragma unroll
    for (int j = 0; j < 8; ++j) {
      t0a[j] = (short)f2b(sv0[j] * b2f((u16)w0a[j]));
      t0b[j] = (short)f2b(sv1[j] * b2f((u16)w0b[j]));
      t1a[j] = (short)f2b(sv0[j] * b2f((u16)w1a[j]));
      t1b[j] = (short)f2b(sv1[j] * b2f((u16)w1b[j]));
    }
#pragma unroll
    for (int nb = 0; nb < 2; ++nb) {
      bf16x8 bA = *(const bf16x8*)(WsvL0 + (size_t)(lg * 32 + nb * 16 + lrow) * 8);
      bf16x8 bB = *(const bf16x8*)(WsvL0 + (size_t)((4 + lg) * 32 + nb * 16 + lrow) * 8);
      f32x4 c = {0.f, 0.f, 0.f, 0.f};
      c = mfma16(t0a, bA, c);
      c = mfma16(t0b, bB, c);
      q0[nb] = c;
      bf16x8 bC = *(const bf16x8*)(WsvL1 + (size_t)(lg * 32 + nb * 16 + lrow) * 8);
      bf16x8 bD = *(const bf16x8*)(WsvL1 + (size_t)((4 + lg) * 32 + nb * 16 + lrow) * 8);
      f32x4 c2 = {0.f, 0.f, 0.f, 0.f};
      c2 = mfma16(t1a, bC, c2);
      c2 = mfma16(t1b, bD, c2);
      q1[nb] = c2;
    }
  }

  // ---- M path: G_k = (v_src . a_k) (.) w2_k ; msg_s = G_0 @ Wvs_0 + G_1 @ Wvs_1
  float a00, a01, a02, a10, a11, a12;
  {
    f32x4 aa = *(const f32x4*)(aE + (size_t)erow * 8);
    f32x2 ab = *(const f32x2*)(aE + (size_t)erow * 8 + 4);
    a00 = aa[0]; a01 = aa[1]; a02 = aa[2]; a10 = aa[3]; a11 = ab[0]; a12 = ab[1];
  }
  float vl[24];
  {
    const float* vp = v + (size_t)src * 96 + lg * 24;
#pragma unroll
    for (int i = 0; i < 6; ++i) *(f32x4*)(vl + 4 * i) = *(const f32x4*)(vp + 4 * i);
  }
  bf16x8 w2a = *(const bf16x8*)(wrow + 128 + lg * 8);
  bf16x8 w2b = *(const bf16x8*)(wrow + 160 + lg * 8);
  bf16x8 ga, gb;
#pragma unroll
  for (int j = 0; j < 8; ++j) {
    float vx = vl[3 * j], vy = vl[3 * j + 1], vz = vl[3 * j + 2];
    float d0 = vx * a00 + vy * a01 + vz * a02;
    float d1 = vx * a10 + vy * a11 + vz * a12;
    ga[j] = (short)f2b(d0 * b2f((u16)w2a[j]));
    gb[j] = (short)f2b(d1 * b2f((u16)w2b[j]));
  }
  f32x4 mS[6];
#pragma unroll
  for (int nb = 0; nb < 6; ++nb) {
    bf16x8 b0 = *(const bf16x8*)(WvsL0 + (size_t)(lg * 96 + nb * 16 + lrow) * 8);
    bf16x8 b1v = *(const bf16x8*)(WvsL1 + (size_t)(lg * 96 + nb * 16 + lrow) * 8);
    f32x4 c = {0.f, 0.f, 0.f, 0.f};
    c = mfma16(ga, b0, c);
    c = mfma16(gb, b1v, c);
    mS[nb] = c;
  }

  // ---- epilogue: scatter rows (this lane owns edges m = 4*lg + r)
  int epos[4];
  float aq[4][6];
#pragma unroll
  for (int r = 0; r < 4; ++r) {
    int er = e0 + 4 * lg + r;
    if (er >= E) er = E - 1;
    epos[r] = pos_of_e[er];
    if (!SZERO) {
      f32x4 aa = *(const f32x4*)(aE + (size_t)er * 8);
      f32x2 ab = *(const f32x2*)(aE + (size_t)er * 8 + 4);
      aq[r][0] = aa[0]; aq[r][1] = aa[1]; aq[r][2] = aa[2];
      aq[r][3] = aa[3]; aq[r][4] = ab[0]; aq[r][5] = ab[1];
    }
  }
#pragma unroll
  for (int nb = 0; nb < 6; ++nb) {
    int n = nb * 16 + lrow;
#pragma unroll
    for (int r = 0; r < 4; ++r)
      msgbuf[(size_t)epos[r] * 192 + n] = f2b(mS[nb][r]);
  }
  if (!SZERO) {
#pragma unroll
    for (int nb = 0; nb < 2; ++nb) {
      int n = nb * 16 + lrow;
#pragma unroll
      for (int r = 0; r < 4; ++r) {
        float Q0v = q0[nb][r], Q1v = q1[nb][r];
#pragma unroll
        for (int c = 0; c < 3; ++c) {
          float val = Q0v * aq[r][c] + Q1v * aq[r][3 + c];
          msgbuf[(size_t)epos[r] * 192 + 96 + c * 32 + n] = f2b(val);
        }
      }
    }
  }
}

// ---------------- fused gather + node update ----------------
template <bool SZERO>
__global__ __launch_bounds__(128) void k_gnode(
    const u16* __restrict__ msg, const int* __restrict__ row_ptr,
    float* __restrict__ s, float* __restrict__ sold, float* __restrict__ v,
    float* __restrict__ vold,
    const float* __restrict__ Amat, const float* __restrict__ Bmat,
    const float* __restrict__ Ws, const float* __restrict__ Wv,
    const float* __restrict__ Wproj, const int* __restrict__ nattr,
    const float* __restrict__ hArr, const float* __restrict__ mixArr, int layer,
    float* __restrict__ xout, int N) {
  int n = blockIdx.x;
  int t = threadIdx.x;
  __shared__ float agg[192];   // [0..95]=agg_s[m]; [96..191]=agg_v at 96+c*32+vch
  __shared__ float srow[64];
  __shared__ float vrow[96];
  __shared__ float gateS[32];
  __shared__ float vnewS[96];
  int start = row_ptr[n], end = row_ptr[n + 1];
  int nacc = SZERO ? 48 : 96;
  if (t < nacc) {
    float lo = 0.f, hi = 0.f;
    for (int p = start; p < end; ++p) {
      u32 w = *(const u32*)(msg + (size_t)p * 192 + t * 2);
      lo += b2f((u16)(w & 0xffffu));
      hi += b2f((u16)(w >> 16));
    }
    agg[2 * t] = lo * INV_SQRT_NN;
    agg[2 * t + 1] = hi * INV_SQRT_NN;
  }
  if (SZERO && t >= 48 && t < 96) {
    agg[2 * t] = 0.f;
    agg[2 * t + 1] = 0.f;
  }
  if (t < 64) srow[t] = s[(size_t)n * 64 + t];
  if (t < 96) vrow[t] = v[(size_t)n * 96 + t];
  __syncthreads();
  int type = nattr[n];
  float hv = hArr[layer];
  float h2 = hv * hv;
  float mx = mixArr[layer];
  float cs = 0.f;
  if (t < 96) {
    cs = agg[t];
    const float* Ac = Amat + (size_t)type * 64 * 96 + t;
#pragma unroll 8
    for (int u = 0; u < 64; ++u) cs += srow[u] * Ac[u * 96];
  }
  if (t >= 64 && t < 96) gateS[t - 64] = 1.0f / (1.0f + __expf(-cs));
  __syncthreads();
  if (t < 64) {
    float gs = cs * (1.0f / (1.0f + __expf(-cs)));
    float sis = 0.f;
#pragma unroll 8
    for (int u = 0; u < 64; ++u) sis += srow[u] * Ws[u * 64 + t];
    float scur = srow[t];
    float sprev = sold[(size_t)n * 64 + t];
    float snew = 2.f * scur - sprev + h2 * (mx * gs + (mx - 1.f) * sis);
    sold[(size_t)n * 64 + t] = scur;
    s[(size_t)n * 64 + t] = snew;
  }
  if (t < 96) {
    int vch = t / 3, c = t - vch * 3;
    float cv = agg[96 + c * 32 + vch];
    const float* Bc = Bmat + (size_t)type * 1024 + vch;
    float scv = 0.f, siv = 0.f;
#pragma unroll 8
    for (int u = 0; u < 32; ++u) {
      float vu = vrow[u * 3 + c];
      scv += vu * Bc[u * 32];
      siv += vu * Wv[u * 32 + vch];
    }
    cv += scv;
    float gv = cv * gateS[vch];
    float vcur = vrow[t];
    float vprev = vold[(size_t)n * 96 + t];
    float vnew = 2.f * vcur - vprev + h2 * (mx * gv + (mx - 1.f) * siv);
    vold[(size_t)n * 96 + t] = vcur;
    v[(size_t)n * 96 + t] = vnew;
    vnewS[t] = vnew;
  }
  __syncthreads();
  if (t < 6) {
    int i = t / 3, c = t - i * 3;
    float acc = 0.f;
#pragma unroll
    for (int vo = 0; vo < 32; ++vo) acc += vnewS[vo * 3 + c] * Wproj[vo * 2 + i];
    xout[(size_t)n * 6 + t] = acc;
  }
}

extern "C" void kernel_launch(void* const* d_in, const int* in_sizes, int n_in,
                              void* d_out, int out_size, void* d_ws, size_t ws_size,
                              hipStream_t stream) {
  const float* x = (const float*)d_in[0];
  const float* emb = (const float*)d_in[1];
  const float* Wup = (const float*)d_in[2];
  const float* Wproj = (const float*)d_in[3];
  const float* fc1 = (const float*)d_in[4];
  const float* b1 = (const float*)d_in[5];
  const float* fc2 = (const float*)d_in[6];
  const float* Wsv = (const float*)d_in[7];
  const float* Wvs = (const float*)d_in[8];
  const float* Wscs = (const float*)d_in[9];
  const float* Wscv = (const float*)d_in[10];
  const float* Ws = (const float*)d_in[11];
  const float* Wv = (const float*)d_in[12];
  const float* hArr = (const float*)d_in[13];
  const float* mixArr = (const float*)d_in[14];
  const int* nattr = (const int*)d_in[15];
  const int* esrc = (const int*)d_in[16];
  const int* edst = (const int*)d_in[17];

  const int N = in_sizes[0] / 6;
  const int E = in_sizes[16];

  float* ws = (float*)d_ws;
  size_t off = 0;
  auto alloc = [&](size_t nf) {
    float* p = ws + off;
    off += (nf + 3) & ~(size_t)3;
    return p;
  };
  float* sbuf = alloc((size_t)N * 64);
  float* sold = alloc((size_t)N * 64);
  float* vbuf = alloc((size_t)N * 96);
  float* vold = alloc((size_t)N * 96);
  float* xcur = alloc((size_t)N * 6);
  float* Amat = alloc((size_t)cL * cNT * 64 * 96);
  float* Bmat = alloc((size_t)cL * cNT * 32 * 32);
  float* fc1T = alloc((size_t)cL * 1024);
  u16* hidb = (u16*)alloc((size_t)E * 32);          // E*64 bf16
  float* aE = alloc((size_t)E * 8);
  u16* fc2L = (u16*)alloc((size_t)cL * 6144);       // L*12288 bf16
  u16* WsvL = (u16*)alloc((size_t)cL * 2048);       // L*2*2048 bf16
  u16* WvsL = (u16*)alloc((size_t)cL * 3072);       // L*2*3072 bf16
  int* deg = (int*)alloc((size_t)(N + 4));
  int* row_ptr = (int*)alloc((size_t)(N + 4));
  int* cursor = (int*)alloc((size_t)(N + 4));
  int* pos_of_e = (int*)alloc((size_t)E);
  u16* msgbuf = (u16*)alloc((size_t)E * 96);        // E*192 bf16

  // init
  hipMemsetAsync(sbuf, 0, sizeof(float) * (size_t)N * 128, stream);  // sbuf + sold
  k_init<<<(N * 32 + 255) / 256, 256, 0, stream>>>(x, Wup, vbuf, vold, xcur, N);
  k_precompA<<<(cL * cNT * 64 * 96 + 255) / 256, 256, 0, stream>>>(emb, Wscs, Amat);
  k_precompB<<<(cL * cNT * 32 * 32 + 255) / 256, 256, 0, stream>>>(emb, Wscv, Bmat);
  k_tr_fc1<<<(cL * 1024 + 255) / 256, 256, 0, stream>>>(fc1, fc1T);
  {
    int tot = cL * 12288 + cL * 2 * 2048 + cL * 2 * 3072;
    k_packB<<<(tot + 255) / 256, 256, 0, stream>>>(fc2, Wsv, Wvs, fc2L, WsvL, WvsL);
  }
  k_zero_i<<<(N + 255) / 256, 256, 0, stream>>>(deg, N);
  k_hist<<<(E + 255) / 256, 256, 0, stream>>>(edst, deg, E);
  k_scan<<<1, 1024, 0, stream>>>(deg, row_ptr, cursor, N);
  k_scatter<<<(E + 255) / 256, 256, 0, stream>>>(edst, cursor, pos_of_e, E);

  int gblocks = (E + 255) / 256;
  int eblocks = ((E + 15) / 16 + 3) / 4;
  for (int l = 0; l < cL; ++l) {
    k_geom<<<gblocks, 256, 0, stream>>>(xcur, esrc, edst, fc1T + l * 1024, b1 + l * 64,
                                        hidb, aE, E);
    if (l == 0)
      k_edge_mfma<true><<<eblocks, 256, 0, stream>>>(
          hidb, aE, sbuf, vbuf, esrc, pos_of_e, fc2L + l * 12288,
          WsvL + l * 4096, WsvL + l * 4096 + 2048,
          WvsL + l * 6144, WvsL + l * 6144 + 3072, msgbuf, E);
    else
      k_edge_mfma<false><<<eblocks, 256, 0, stream>>>(
          hidb, aE, sbuf, vbuf, esrc, pos_of_e, fc2L + l * 12288,
          WsvL + l * 4096, WsvL + l * 4096 + 2048,
          WvsL + l * 6144, WvsL + l * 6144 + 3072, msgbuf, E);
    float* xout = (l == cL - 1) ? (float*)d_out : xcur;
    if (l == 0)
      k_gnode<true><<<N, 128, 0, stream>>>(
          msgbuf, row_ptr, sbuf, sold, vbuf, vold, Amat + (size_t)l * cNT * 64 * 96,
          Bmat + (size_t)l * cNT * 1024, Ws + l * 4096, Wv + l * 1024, Wproj, nattr,
          hArr, mixArr, l, xout, N);
    else
      k_gnode<false><<<N, 128, 0, stream>>>(
          msgbuf, row_ptr, sbuf, sold, vbuf, vold, Amat + (size_t)l * cNT * 64 * 96,
          Bmat + (size_t)l * cNT * 1024, Ws + l * 4096, Wv + l * 1024, Wproj, nattr,
          hArr, mixArr, l, xout, N);
  }
}

// Round 6
// 707.701 us; speedup vs baseline: 8.2798x; 1.0553x over previous
//
#include <hip/hip_runtime.h>
#include <math.h>

constexpr int cNS = 64, cNV = 32, cNB = 8, cL = 4, cEMB = 32, cNT = 10;
constexpr float PI_F = 3.14159265358979323846f;
constexpr float INV_SQRT_NN = 0.17677669529663687f;   // 1/sqrt(32)
constexpr float BESSEL_C = 2.3094010767585034f;       // sqrt(2/3)*sqrt(8)
constexpr float SQRT3 = 1.7320508075688772f;

typedef unsigned short u16;
typedef unsigned int u32;
typedef __attribute__((ext_vector_type(8))) short bf16x8;
typedef __attribute__((ext_vector_type(4))) float f32x4;
typedef __attribute__((ext_vector_type(2))) float f32x2;
typedef __attribute__((ext_vector_type(4))) int i32x4;

__device__ __forceinline__ u16 f2b(float x) {   // f32 -> bf16 RNE
  u32 u = __float_as_uint(x);
  return (u16)((u + 0x7fffu + ((u >> 16) & 1u)) >> 16);
}
__device__ __forceinline__ float b2f(u16 h) { return __uint_as_float(((u32)h) << 16); }

__device__ __forceinline__ f32x4 mfma16(bf16x8 a, bf16x8 b, f32x4 c) {
  return __builtin_amdgcn_mfma_f32_16x16x32_bf16(a, b, c, 0, 0, 0);
}

// ---------------- precompute kernels ----------------

__global__ void k_precompA(const float* __restrict__ emb, const float* __restrict__ Wss,
                           float* __restrict__ A) {
  int idx = blockIdx.x * 256 + threadIdx.x;
  if (idx >= cL * cNT * 64 * 96) return;
  int m = idx % 96;
  int u = (idx / 96) % 64;
  int t = (idx / (96 * 64)) % cNT;
  int l = idx / (96 * 64 * cNT);
  float acc = 0.f;
#pragma unroll
  for (int e = 0; e < 32; ++e)
    acc += emb[t * 32 + e] * Wss[((size_t)(l * 64 + u) * 32 + e) * 96 + m];
  A[idx] = acc;
}

__global__ void k_precompB(const float* __restrict__ emb, const float* __restrict__ Wsv_,
                           float* __restrict__ B) {
  int idx = blockIdx.x * 256 + threadIdx.x;
  if (idx >= cL * cNT * 32 * 32) return;
  int vo = idx % 32;
  int u = (idx / 32) % 32;
  int t = (idx / 1024) % cNT;
  int l = idx / (1024 * cNT);
  float acc = 0.f;
#pragma unroll
  for (int e = 0; e < 32; ++e)
    acc += emb[t * 32 + e] * Wsv_[((size_t)(l * 32 + u) * 32 + e) * 32 + vo];
  B[idx] = acc;
}

// fc1T[l][j][t] = fc1[l][t][j]
__global__ void k_tr_fc1(const float* __restrict__ fc1, float* __restrict__ fc1T) {
  int idx = blockIdx.x * 256 + threadIdx.x;
  if (idx >= cL * 1024) return;
  int l = idx / 1024, p = idx % 1024;
  int j = p / 16, t = p % 16;
  fc1T[idx] = fc1[l * 1024 + t * 64 + j];
}

// pack fc2 / W_sv / W_vs into bf16 MFMA-B layouts: BL[(k/8)*N*8 + n*8 + (k%8)]
__global__ void k_packB(const float* __restrict__ fc2, const float* __restrict__ Wsv,
                        const float* __restrict__ Wvs, u16* __restrict__ fc2L,
                        u16* __restrict__ WsvL, u16* __restrict__ WvsL) {
  int idx = blockIdx.x * 256 + threadIdx.x;
  const int T1 = cL * 12288, T2 = cL * 2 * 2048, T3 = cL * 2 * 3072;
  if (idx < T1) {
    int l = idx / 12288, r = idx % 12288;
    int ki = r & 7, tt = r >> 3;
    int nn = tt % 192, kq = tt / 192;
    fc2L[idx] = f2b(fc2[((size_t)(l * 64) + kq * 8 + ki) * 192 + nn]);
  } else if (idx < T1 + T2) {
    int r0 = idx - T1;
    int l = r0 / 4096, r1 = r0 % 4096;
    int k2 = r1 / 2048, r = r1 % 2048;
    int ki = r & 7, tt = r >> 3;
    int mm = tt % 32, kq = tt / 32;
    WsvL[r0] = f2b(Wsv[((size_t)((l * 64 + kq * 8 + ki) * 2) + k2) * 32 + mm]);
  } else if (idx < T1 + T2 + T3) {
    int r0 = idx - T1 - T2;
    int l = r0 / 6144, r1 = r0 % 6144;
    int k2 = r1 / 3072, r = r1 % 3072;
    int ki = r & 7, tt = r >> 3;
    int mm = tt % 96, kq = tt / 96;
    WvsL[r0] = f2b(Wvs[((size_t)((l * 32 + kq * 8 + ki) * 2) + k2) * 96 + mm]);
  }
}

__global__ void k_init(const float* __restrict__ x, const float* __restrict__ Wup,
                       float* __restrict__ v, float* __restrict__ v_old,
                       float* __restrict__ xcur, int N) {
  int idx = blockIdx.x * 256 + threadIdx.x;
  if (idx >= N * 32) return;
  int n = idx >> 5, vc = idx & 31;
  float w0 = Wup[vc], w1 = Wup[32 + vc];
#pragma unroll
  for (int c = 0; c < 3; ++c) {
    float val = x[n * 6 + c] * w0 + x[n * 6 + 3 + c] * w1;
    v[idx * 3 + c] = val;
    v_old[idx * 3 + c] = val;
  }
  if (vc < 6) xcur[n * 6 + vc] = x[n * 6 + vc];
}

// ---------------- CSR build ----------------

__global__ void k_zero_i(int* __restrict__ p, int n) {
  int i = blockIdx.x * 256 + threadIdx.x;
  if (i < n) p[i] = 0;
}

__global__ void k_hist(const int* __restrict__ edst, int* __restrict__ deg, int E) {
  int e = blockIdx.x * 256 + threadIdx.x;
  if (e < E) atomicAdd(&deg[edst[e]], 1);
}

__global__ __launch_bounds__(1024) void k_scan(const int* __restrict__ deg,
                                               int* __restrict__ row_ptr,
                                               int* __restrict__ cursor, int N) {
  __shared__ int part[1024];
  int t = threadIdx.x;
  int chunk = (N + 1023) / 1024;
  int base = t * chunk;
  int sum = 0;
  for (int i = 0; i < chunk; ++i) {
    int idx = base + i;
    if (idx < N) sum += deg[idx];
  }
  part[t] = sum;
  __syncthreads();
  for (int off = 1; off < 1024; off <<= 1) {
    int val = (t >= off) ? part[t - off] : 0;
    __syncthreads();
    part[t] += val;
    __syncthreads();
  }
  int run = (t > 0) ? part[t - 1] : 0;
  for (int i = 0; i < chunk; ++i) {
    int idx = base + i;
    if (idx < N) {
      row_ptr[idx] = run;
      cursor[idx] = run;
      run += deg[idx];
    }
  }
  if (t == 1023) row_ptr[N] = part[1023];
}

// scatter edges into CSR order: esrc_s / edst_s indexed by sorted position
__global__ void k_scatter(const int* __restrict__ esrc, const int* __restrict__ edst,
                          int* __restrict__ cursor, int* __restrict__ esrc_s,
                          int* __restrict__ edst_s, int E) {
  int e = blockIdx.x * 256 + threadIdx.x;
  if (e < E) {
    int d = edst[e];
    int p = atomicAdd(&cursor[d], 1);
    esrc_s[p] = esrc[e];
    edst_s[p] = d;
  }
}

// ---------------- per-edge geometry + small MLP (fp32), sorted order ----------------
__global__ __launch_bounds__(256) void k_geom(
    const float* __restrict__ xcur, const int* __restrict__ esrc_s,
    const int* __restrict__ edst_s, const float* __restrict__ fc1T,
    const float* __restrict__ b1, u16* __restrict__ hidb, float* __restrict__ aE, int E) {
  int e = blockIdx.x * 256 + threadIdx.x;
  if (e >= E) return;
  int src = esrc_s[e], dst = edst_s[e];

  float xs[6], xd[6];
  {
    const float2* ps = (const float2*)(xcur + (size_t)src * 6);
    const float2* pd = (const float2*)(xcur + (size_t)dst * 6);
    float2 A0 = ps[0], A1 = ps[1], A2 = ps[2];
    float2 B0 = pd[0], B1 = pd[1], B2 = pd[2];
    xs[0] = A0.x; xs[1] = A0.y; xs[2] = A1.x; xs[3] = A1.y; xs[4] = A2.x; xs[5] = A2.y;
    xd[0] = B0.x; xd[1] = B0.y; xd[2] = B1.x; xd[3] = B1.y; xd[4] = B2.x; xd[5] = B2.y;
  }

  float f[16], av[6];
#pragma unroll
  for (int i = 0; i < 2; ++i) {
    float vx = xs[3 * i + 0] - xd[3 * i + 0];
    float vy = xs[3 * i + 1] - xd[3 * i + 1];
    float vz = xs[3 * i + 2] - xd[3 * i + 2];
    float r2 = vx * vx + vy * vy + vz * vz;
    float rr = sqrtf(r2);
    float invr = 1.0f / rr;
    float th = (PI_F / 3.0f) * rr;
    float s1, c1;
    __sincosf(th, &s1, &c1);
    float twc = 2.0f * c1;
    float snm = 0.f, sn = s1;
    float fc = BESSEL_C * invr;
#pragma unroll
    for (int nn = 0; nn < 8; ++nn) {
      f[8 * i + nn] = fc * sn;
      float nx = twc * sn - snm;
      snm = sn;
      sn = nx;
    }
    float uu = (2.0f / 3.0f) * rr - 2.0f;
    float cut;
    if (uu > 0.f) cut = 0.f;
    else if (uu < -1.f) cut = 1.f;
    else cut = (1.0f - __cosf(PI_F * uu)) * 0.5f;
    float sc = cut * SQRT3 * invr;
    av[3 * i + 0] = vx * sc; av[3 * i + 1] = vy * sc; av[3 * i + 2] = vz * sc;
  }
  {
    f32x4 A1v = {av[0], av[1], av[2], av[3]};
    f32x4 A2v = {av[4], av[5], 0.f, 0.f};
    *(f32x4*)(aE + (size_t)e * 8) = A1v;
    *(f32x4*)(aE + (size_t)e * 8 + 4) = A2v;
  }

  u32 hb[32];
#pragma unroll 4
  for (int j = 0; j < 64; j += 2) {
    const f32x4* r0 = (const f32x4*)(fc1T + j * 16);
    const f32x4* r1 = (const f32x4*)(fc1T + (j + 1) * 16);
    float acc0 = b1[j], acc1 = b1[j + 1];
#pragma unroll
    for (int c4 = 0; c4 < 4; ++c4) {
      f32x4 w0 = r0[c4], w1 = r1[c4];
      acc0 += f[4 * c4] * w0[0] + f[4 * c4 + 1] * w0[1] + f[4 * c4 + 2] * w0[2] + f[4 * c4 + 3] * w0[3];
      acc1 += f[4 * c4] * w1[0] + f[4 * c4 + 1] * w1[1] + f[4 * c4 + 2] * w1[2] + f[4 * c4 + 3] * w1[3];
    }
    float h0 = acc0 * (1.0f / (1.0f + __expf(-acc0)));
    float h1 = acc1 * (1.0f / (1.0f + __expf(-acc1)));
    hb[j >> 1] = (u32)f2b(h0) | ((u32)f2b(h1) << 16);
  }
  u32* dst4 = (u32*)(hidb + (size_t)e * 64);
#pragma unroll
  for (int i = 0; i < 32; ++i) dst4[i] = hb[i];
}

// ---------------- MFMA edge kernel: wave = 16 consecutive (CSR-sorted) edges --------
// msg row (bf16, stride 192): [0..95] msg_s[m], [96..191] msg_v at 96 + c*32 + m'
template <bool SZERO>
__global__ __launch_bounds__(256) void k_edge_mfma(
    const u16* __restrict__ hidb, const float* __restrict__ aE,
    const float* __restrict__ s, const float* __restrict__ v,
    const int* __restrict__ esrc_s,
    const u16* __restrict__ fc2L, const u16* __restrict__ WsvL0,
    const u16* __restrict__ WsvL1, const u16* __restrict__ WvsL0,
    const u16* __restrict__ WvsL1, u16* __restrict__ msgbuf, int E) {
  __shared__ u16 wbAll[4][16 * 200];   // per-wave staging (w GEMM result, then out rows)
  __shared__ float aAll[4][16][6];
  int wid = threadIdx.x >> 6, lane = threadIdx.x & 63;
  int e0 = (blockIdx.x * 4 + wid) * 16;
  if (e0 >= E) return;
  u16* wb = wbAll[wid];
  int lrow = lane & 15, lg = lane >> 4;
  int prow = e0 + lrow;
  if (prow >= E) prow = E - 1;

  // hid fragments (coalesced; sorted order)
  bf16x8 ha = *(const bf16x8*)(hidb + (size_t)prow * 64 + lg * 8);
  bf16x8 hbf = *(const bf16x8*)(hidb + (size_t)prow * 64 + 32 + lg * 8);
  // a-vectors -> LDS once (lg==0 lanes)
  if (lg == 0) {
    f32x4 aa = *(const f32x4*)(aE + (size_t)prow * 8);
    f32x2 ab = *(const f32x2*)(aE + (size_t)prow * 8 + 4);
    float* ap = aAll[wid][lrow];
    ap[0] = aa[0]; ap[1] = aa[1]; ap[2] = aa[2]; ap[3] = aa[3]; ap[4] = ab[0]; ap[5] = ab[1];
  }

  // ---- GEMM2: w[16,192] = hid[16,64] @ fc2[64,192], store bf16 to LDS permuted
#pragma unroll
  for (int nb = (SZERO ? 8 : 0); nb < 12; ++nb) {
    bf16x8 b0 = *(const bf16x8*)(fc2L + (size_t)(lg * 192 + nb * 16 + lrow) * 8);
    bf16x8 b1v = *(const bf16x8*)(fc2L + (size_t)((4 + lg) * 192 + nb * 16 + lrow) * 8);
    f32x4 c = {0.f, 0.f, 0.f, 0.f};
    c = mfma16(ha, b0, c);
    c = mfma16(hbf, b1v, c);
    int n = nb * 16 + lrow;
    int pn = (n < 128) ? ((n & 1) * 64 + (n >> 1)) : (128 + (n & 1) * 32 + ((n - 128) >> 1));
    int rbase = 4 * lg * 200 + pn;
    wb[rbase] = f2b(c[0]);
    wb[rbase + 200] = f2b(c[1]);
    wb[rbase + 400] = f2b(c[2]);
    wb[rbase + 600] = f2b(c[3]);
  }
  asm volatile("s_waitcnt lgkmcnt(0)" ::: "memory");

  int src = esrc_s[prow];
  const u16* wrow = wb + lrow * 200;

  // ---- Q path: T_k = s_src (.) w1_k ; Q_k = T_k @ W_sv_k
  f32x4 q0[2], q1[2];
  if (!SZERO) {
    const float* sp = s + (size_t)src * 64;
    float sv0[8], sv1[8];
    *(f32x4*)(sv0) = *(const f32x4*)(sp + lg * 8);
    *(f32x4*)(sv0 + 4) = *(const f32x4*)(sp + lg * 8 + 4);
    *(f32x4*)(sv1) = *(const f32x4*)(sp + 32 + lg * 8);
    *(f32x4*)(sv1 + 4) = *(const f32x4*)(sp + 32 + lg * 8 + 4);
    bf16x8 w0a = *(const bf16x8*)(wrow + lg * 8);
    bf16x8 w0b = *(const bf16x8*)(wrow + 32 + lg * 8);
    bf16x8 w1a = *(const bf16x8*)(wrow + 64 + lg * 8);
    bf16x8 w1b = *(const bf16x8*)(wrow + 96 + lg * 8);
    bf16x8 t0a, t0b, t1a, t1b;
#pragma unroll
    for (int j = 0; j < 8; ++j) {
      t0a[j] = (short)f2b(sv0[j] * b2f((u16)w0a[j]));
      t0b[j] = (short)f2b(sv1[j] * b2f((u16)w0b[j]));
      t1a[j] = (short)f2b(sv0[j] * b2f((u16)w1a[j]));
      t1b[j] = (short)f2b(sv1[j] * b2f((u16)w1b[j]));
    }
#pragma unroll
    for (int nb = 0; nb < 2; ++nb) {
      bf16x8 bA = *(const bf16x8*)(WsvL0 + (size_t)(lg * 32 + nb * 16 + lrow) * 8);
      bf16x8 bB = *(const bf16x8*)(WsvL0 + (size_t)((4 + lg) * 32 + nb * 16 + lrow) * 8);
      f32x4 c = {0.f, 0.f, 0.f, 0.f};
      c = mfma16(t0a, bA, c);
      c = mfma16(t0b, bB, c);
      q0[nb] = c;
      bf16x8 bC = *(const bf16x8*)(WsvL1 + (size_t)(lg * 32 + nb * 16 + lrow) * 8);
      bf16x8 bD = *(const bf16x8*)(WsvL1 + (size_t)((4 + lg) * 32 + nb * 16 + lrow) * 8);
      f32x4 c2 = {0.f, 0.f, 0.f, 0.f};
      c2 = mfma16(t1a, bC, c2);
      c2 = mfma16(t1b, bD, c2);
      q1[nb] = c2;
    }
  }

  // ---- M path: G_k = (v_src . a_k) (.) w2_k ; msg_s = G_0 @ Wvs_0 + G_1 @ Wvs_1
  float a00, a01, a02, a10, a11, a12;
  {
    const float* ap = aAll[wid][lrow];
    a00 = ap[0]; a01 = ap[1]; a02 = ap[2]; a10 = ap[3]; a11 = ap[4]; a12 = ap[5];
  }
  float vl[24];
  {
    const float* vp = v + (size_t)src * 96 + lg * 24;
#pragma unroll
    for (int i = 0; i < 6; ++i) *(f32x4*)(vl + 4 * i) = *(const f32x4*)(vp + 4 * i);
  }
  bf16x8 w2a = *(const bf16x8*)(wrow + 128 + lg * 8);
  bf16x8 w2b = *(const bf16x8*)(wrow + 160 + lg * 8);
  bf16x8 ga, gb;
#pragma unroll
  for (int j = 0; j < 8; ++j) {
    float vx = vl[3 * j], vy = vl[3 * j + 1], vz = vl[3 * j + 2];
    float d0 = vx * a00 + vy * a01 + vz * a02;
    float d1 = vx * a10 + vy * a11 + vz * a12;
    ga[j] = (short)f2b(d0 * b2f((u16)w2a[j]));
    gb[j] = (short)f2b(d1 * b2f((u16)w2b[j]));
  }
  f32x4 mS[6];
#pragma unroll
  for (int nb = 0; nb < 6; ++nb) {
    bf16x8 b0 = *(const bf16x8*)(WvsL0 + (size_t)(lg * 96 + nb * 16 + lrow) * 8);
    bf16x8 b1v = *(const bf16x8*)(WvsL1 + (size_t)(lg * 96 + nb * 16 + lrow) * 8);
    f32x4 c = {0.f, 0.f, 0.f, 0.f};
    c = mfma16(ga, b0, c);
    c = mfma16(gb, b1v, c);
    mS[nb] = c;
  }

  // ---- stage final msg rows into wb (overwrite w; all wb reads already consumed)
  asm volatile("s_waitcnt lgkmcnt(0)" ::: "memory");
#pragma unroll
  for (int nb = 0; nb < 6; ++nb) {
#pragma unroll
    for (int r = 0; r < 4; ++r)
      wb[(4 * lg + r) * 200 + nb * 16 + lrow] = f2b(mS[nb][r]);
  }
  if (!SZERO) {
#pragma unroll
    for (int nb = 0; nb < 2; ++nb) {
#pragma unroll
      for (int r = 0; r < 4; ++r) {
        int el = 4 * lg + r;
        const float* ap = aAll[wid][el];
        float Q0v = q0[nb][r], Q1v = q1[nb][r];
#pragma unroll
        for (int c = 0; c < 3; ++c)
          wb[el * 200 + 96 + c * 32 + nb * 16 + lrow] = f2b(Q0v * ap[c] + Q1v * ap[3 + c]);
      }
    }
  }
  asm volatile("s_waitcnt lgkmcnt(0)" ::: "memory");

  // ---- cooperative coalesced write: 16 consecutive rows x 192 u16
  int orow = lane >> 2, oq = lane & 3;
  if (e0 + orow < E) {
    u16* gdst = msgbuf + (size_t)(e0 + orow) * 192;
    const int NIT = SZERO ? 3 : 6;
#pragma unroll
    for (int it = 0; it < NIT; ++it) {
      int col = oq * 8 + it * 32;
      i32x4 d = *(const i32x4*)(wb + orow * 200 + col);
      *(i32x4*)(gdst + col) = d;
    }
  }
}

// ---------------- fused gather + node update ----------------
template <bool SZERO>
__global__ __launch_bounds__(128) void k_gnode(
    const u16* __restrict__ msg, const int* __restrict__ row_ptr,
    float* __restrict__ s, float* __restrict__ sold, float* __restrict__ v,
    float* __restrict__ vold,
    const float* __restrict__ Amat, const float* __restrict__ Bmat,
    const float* __restrict__ Ws, const float* __restrict__ Wv,
    const float* __restrict__ Wproj, const int* __restrict__ nattr,
    const float* __restrict__ hArr, const float* __restrict__ mixArr, int layer,
    float* __restrict__ xout, int N) {
  int n = blockIdx.x;
  int t = threadIdx.x;
  __shared__ float agg[192];   // [0..95]=agg_s[m]; [96..191]=agg_v at 96+c*32+vch
  __shared__ float srow[64];
  __shared__ float vrow[96];
  __shared__ float gateS[32];
  __shared__ float vnewS[96];
  int start = row_ptr[n], end = row_ptr[n + 1];
  int nacc = SZERO ? 48 : 96;
  if (t < nacc) {
    float lo = 0.f, hi = 0.f;
    for (int p = start; p < end; ++p) {
      u32 w = *(const u32*)(msg + (size_t)p * 192 + t * 2);
      lo += b2f((u16)(w & 0xffffu));
      hi += b2f((u16)(w >> 16));
    }
    agg[2 * t] = lo * INV_SQRT_NN;
    agg[2 * t + 1] = hi * INV_SQRT_NN;
  }
  if (SZERO && t >= 48 && t < 96) {
    agg[2 * t] = 0.f;
    agg[2 * t + 1] = 0.f;
  }
  if (t < 64) srow[t] = s[(size_t)n * 64 + t];
  if (t < 96) vrow[t] = v[(size_t)n * 96 + t];
  __syncthreads();
  int type = nattr[n];
  float hv = hArr[layer];
  float h2 = hv * hv;
  float mx = mixArr[layer];
  float cs = 0.f;
  if (t < 96) {
    cs = agg[t];
    const float* Ac = Amat + (size_t)type * 64 * 96 + t;
#pragma unroll 8
    for (int u = 0; u < 64; ++u) cs += srow[u] * Ac[u * 96];
  }
  if (t >= 64 && t < 96) gateS[t - 64] = 1.0f / (1.0f + __expf(-cs));
  __syncthreads();
  if (t < 64) {
    float gs = cs * (1.0f / (1.0f + __expf(-cs)));
    float sis = 0.f;
#pragma unroll 8
    for (int u = 0; u < 64; ++u) sis += srow[u] * Ws[u * 64 + t];
    float scur = srow[t];
    float sprev = sold[(size_t)n * 64 + t];
    float snew = 2.f * scur - sprev + h2 * (mx * gs + (mx - 1.f) * sis);
    sold[(size_t)n * 64 + t] = scur;
    s[(size_t)n * 64 + t] = snew;
  }
  if (t < 96) {
    int vch = t / 3, c = t - vch * 3;
    float cv = agg[96 + c * 32 + vch];
    const float* Bc = Bmat + (size_t)type * 1024 + vch;
    float scv = 0.f, siv = 0.f;
#pragma unroll 8
    for (int u = 0; u < 32; ++u) {
      float vu = vrow[u * 3 + c];
      scv += vu * Bc[u * 32];
      siv += vu * Wv[u * 32 + vch];
    }
    cv += scv;
    float gv = cv * gateS[vch];
    float vcur = vrow[t];
    float vprev = vold[(size_t)n * 96 + t];
    float vnew = 2.f * vcur - vprev + h2 * (mx * gv + (mx - 1.f) * siv);
    vold[(size_t)n * 96 + t] = vcur;
    v[(size_t)n * 96 + t] = vnew;
    vnewS[t] = vnew;
  }
  __syncthreads();
  if (t < 6) {
    int i = t / 3, c = t - i * 3;
    float acc = 0.f;
#pragma unroll
    for (int vo = 0; vo < 32; ++vo) acc += vnewS[vo * 3 + c] * Wproj[vo * 2 + i];
    xout[(size_t)n * 6 + t] = acc;
  }
}

extern "C" void kernel_launch(void* const* d_in, const int* in_sizes, int n_in,
                              void* d_out, int out_size, void* d_ws, size_t ws_size,
                              hipStream_t stream) {
  const float* x = (const float*)d_in[0];
  const float* emb = (const float*)d_in[1];
  const float* Wup = (const float*)d_in[2];
  const float* Wproj = (const float*)d_in[3];
  const float* fc1 = (const float*)d_in[4];
  const float* b1 = (const float*)d_in[5];
  const float* fc2 = (const float*)d_in[6];
  const float* Wsv = (const float*)d_in[7];
  const float* Wvs = (const float*)d_in[8];
  const float* Wscs = (const float*)d_in[9];
  const float* Wscv = (const float*)d_in[10];
  const float* Ws = (const float*)d_in[11];
  const float* Wv = (const float*)d_in[12];
  const float* hArr = (const float*)d_in[13];
  const float* mixArr = (const float*)d_in[14];
  const int* nattr = (const int*)d_in[15];
  const int* esrc = (const int*)d_in[16];
  const int* edst = (const int*)d_in[17];

  const int N = in_sizes[0] / 6;
  const int E = in_sizes[16];

  float* ws = (float*)d_ws;
  size_t off = 0;
  auto alloc = [&](size_t nf) {
    float* p = ws + off;
    off += (nf + 3) & ~(size_t)3;
    return p;
  };
  float* sbuf = alloc((size_t)N * 64);
  float* sold = alloc((size_t)N * 64);
  float* vbuf = alloc((size_t)N * 96);
  float* vold = alloc((size_t)N * 96);
  float* xcur = alloc((size_t)N * 6);
  float* Amat = alloc((size_t)cL * cNT * 64 * 96);
  float* Bmat = alloc((size_t)cL * cNT * 32 * 32);
  float* fc1T = alloc((size_t)cL * 1024);
  u16* hidb = (u16*)alloc((size_t)E * 32);          // E*64 bf16
  float* aE = alloc((size_t)E * 8);
  u16* fc2L = (u16*)alloc((size_t)cL * 6144);       // L*12288 bf16
  u16* WsvL = (u16*)alloc((size_t)cL * 2048);       // L*2*2048 bf16
  u16* WvsL = (u16*)alloc((size_t)cL * 3072);       // L*2*3072 bf16
  int* deg = (int*)alloc((size_t)(N + 4));
  int* row_ptr = (int*)alloc((size_t)(N + 4));
  int* cursor = (int*)alloc((size_t)(N + 4));
  int* esrc_s = (int*)alloc((size_t)E);
  int* edst_s = (int*)alloc((size_t)E);
  u16* msgbuf = (u16*)alloc((size_t)E * 96);        // E*192 bf16

  // init
  hipMemsetAsync(sbuf, 0, sizeof(float) * (size_t)N * 128, stream);  // sbuf + sold
  k_init<<<(N * 32 + 255) / 256, 256, 0, stream>>>(x, Wup, vbuf, vold, xcur, N);
  k_precompA<<<(cL * cNT * 64 * 96 + 255) / 256, 256, 0, stream>>>(emb, Wscs, Amat);
  k_precompB<<<(cL * cNT * 32 * 32 + 255) / 256, 256, 0, stream>>>(emb, Wscv, Bmat);
  k_tr_fc1<<<(cL * 1024 + 255) / 256, 256, 0, stream>>>(fc1, fc1T);
  {
    int tot = cL * 12288 + cL * 2 * 2048 + cL * 2 * 3072;
    k_packB<<<(tot + 255) / 256, 256, 0, stream>>>(fc2, Wsv, Wvs, fc2L, WsvL, WvsL);
  }
  k_zero_i<<<(N + 255) / 256, 256, 0, stream>>>(deg, N);
  k_hist<<<(E + 255) / 256, 256, 0, stream>>>(edst, deg, E);
  k_scan<<<1, 1024, 0, stream>>>(deg, row_ptr, cursor, N);
  k_scatter<<<(E + 255) / 256, 256, 0, stream>>>(esrc, edst, cursor, esrc_s, edst_s, E);

  int gblocks = (E + 255) / 256;
  int eblocks = ((E + 15) / 16 + 3) / 4;
  for (int l = 0; l < cL; ++l) {
    k_geom<<<gblocks, 256, 0, stream>>>(xcur, esrc_s, edst_s, fc1T + l * 1024, b1 + l * 64,
                                        hidb, aE, E);
    if (l == 0)
      k_edge_mfma<true><<<eblocks, 256, 0, stream>>>(
          hidb, aE, sbuf, vbuf, esrc_s, fc2L + l * 12288,
          WsvL + l * 4096, WsvL + l * 4096 + 2048,
          WvsL + l * 6144, WvsL + l * 6144 + 3072, msgbuf, E);
    else
      k_edge_mfma<false><<<eblocks, 256, 0, stream>>>(
          hidb, aE, sbuf, vbuf, esrc_s, fc2L + l * 12288,
          WsvL + l * 4096, WsvL + l * 4096 + 2048,
          WvsL + l * 6144, WvsL + l * 6144 + 3072, msgbuf, E);
    float* xout = (l == cL - 1) ? (float*)d_out : xcur;
    if (l == 0)
      k_gnode<true><<<N, 128, 0, stream>>>(
          msgbuf, row_ptr, sbuf, sold, vbuf, vold, Amat + (size_t)l * cNT * 64 * 96,
          Bmat + (size_t)l * cNT * 1024, Ws + l * 4096, Wv + l * 1024, Wproj, nattr,
          hArr, mixArr, l, xout, N);
    else
      k_gnode<false><<<N, 128, 0, stream>>>(
          msgbuf, row_ptr, sbuf, sold, vbuf, vold, Amat + (size_t)l * cNT * 64 * 96,
          Bmat + (size_t)l * cNT * 1024, Ws + l * 4096, Wv + l * 1024, Wproj, nattr,
          hArr, mixArr, l, xout, N);
  }
}

// Round 7
// 558.031 us; speedup vs baseline: 10.5006x; 1.2682x over previous
//
#include <hip/hip_runtime.h>
#include <math.h>

constexpr int cNS = 64, cNV = 32, cNB = 8, cL = 4, cEMB = 32, cNT = 10;
constexpr float PI_F = 3.14159265358979323846f;
constexpr float INV_SQRT_NN = 0.17677669529663687f;   // 1/sqrt(32)
constexpr float BESSEL_C = 2.3094010767585034f;       // sqrt(2/3)*sqrt(8)
constexpr float SQRT3 = 1.7320508075688772f;

typedef unsigned short u16;
typedef unsigned int u32;
typedef __attribute__((ext_vector_type(8))) short bf16x8;
typedef __attribute__((ext_vector_type(4))) float f32x4;
typedef __attribute__((ext_vector_type(2))) float f32x2;
typedef __attribute__((ext_vector_type(4))) int i32x4;

__device__ __forceinline__ u16 f2b(float x) {   // f32 -> bf16 RNE
  u32 u = __float_as_uint(x);
  return (u16)((u + 0x7fffu + ((u >> 16) & 1u)) >> 16);
}
__device__ __forceinline__ float b2f(u16 h) { return __uint_as_float(((u32)h) << 16); }

__device__ __forceinline__ f32x4 mfma16(bf16x8 a, bf16x8 b, f32x4 c) {
  return __builtin_amdgcn_mfma_f32_16x16x32_bf16(a, b, c, 0, 0, 0);
}

// ---------------- precompute kernels ----------------

__global__ void k_precompA(const float* __restrict__ emb, const float* __restrict__ Wss,
                           float* __restrict__ A) {
  int idx = blockIdx.x * 256 + threadIdx.x;
  if (idx >= cL * cNT * 64 * 96) return;
  int m = idx % 96;
  int u = (idx / 96) % 64;
  int t = (idx / (96 * 64)) % cNT;
  int l = idx / (96 * 64 * cNT);
  float acc = 0.f;
#pragma unroll
  for (int e = 0; e < 32; ++e)
    acc += emb[t * 32 + e] * Wss[((size_t)(l * 64 + u) * 32 + e) * 96 + m];
  A[idx] = acc;
}

__global__ void k_precompB(const float* __restrict__ emb, const float* __restrict__ Wsv_,
                           float* __restrict__ B) {
  int idx = blockIdx.x * 256 + threadIdx.x;
  if (idx >= cL * cNT * 32 * 32) return;
  int vo = idx % 32;
  int u = (idx / 32) % 32;
  int t = (idx / 1024) % cNT;
  int l = idx / (1024 * cNT);
  float acc = 0.f;
#pragma unroll
  for (int e = 0; e < 32; ++e)
    acc += emb[t * 32 + e] * Wsv_[((size_t)(l * 32 + u) * 32 + e) * 32 + vo];
  B[idx] = acc;
}

// pack fc2 / W_sv / W_vs / fc1 into bf16 MFMA-B layouts: BL[(k/8)*N*8 + n*8 + (k%8)]
// fc1L has kq padded to 4 (kq>=2 -> zeros) so the MLP MFMA can load unconditionally.
__global__ void k_packB(const float* __restrict__ fc2, const float* __restrict__ Wsv,
                        const float* __restrict__ Wvs, const float* __restrict__ fc1,
                        u16* __restrict__ fc2L, u16* __restrict__ WsvL,
                        u16* __restrict__ WvsL, u16* __restrict__ fc1L) {
  int idx = blockIdx.x * 256 + threadIdx.x;
  const int T1 = cL * 12288, T2 = cL * 2 * 2048, T3 = cL * 2 * 3072, T4 = cL * 2048;
  if (idx < T1) {
    int l = idx / 12288, r = idx % 12288;
    int ki = r & 7, tt = r >> 3;
    int nn = tt % 192, kq = tt / 192;
    fc2L[idx] = f2b(fc2[((size_t)(l * 64) + kq * 8 + ki) * 192 + nn]);
  } else if (idx < T1 + T2) {
    int r0 = idx - T1;
    int l = r0 / 4096, r1 = r0 % 4096;
    int k2 = r1 / 2048, r = r1 % 2048;
    int ki = r & 7, tt = r >> 3;
    int mm = tt % 32, kq = tt / 32;
    WsvL[r0] = f2b(Wsv[((size_t)((l * 64 + kq * 8 + ki) * 2) + k2) * 32 + mm]);
  } else if (idx < T1 + T2 + T3) {
    int r0 = idx - T1 - T2;
    int l = r0 / 6144, r1 = r0 % 6144;
    int k2 = r1 / 3072, r = r1 % 3072;
    int ki = r & 7, tt = r >> 3;
    int mm = tt % 96, kq = tt / 96;
    WvsL[r0] = f2b(Wvs[((size_t)((l * 32 + kq * 8 + ki) * 2) + k2) * 96 + mm]);
  } else if (idx < T1 + T2 + T3 + T4) {
    int r0 = idx - T1 - T2 - T3;
    int l = r0 / 2048, r1 = r0 % 2048;
    int kq = r1 / 512, rem = r1 % 512;
    int n = rem / 8, ki = rem & 7;
    fc1L[r0] = (kq < 2) ? f2b(fc1[l * 1024 + (kq * 8 + ki) * 64 + n]) : (u16)0;
  }
}

__global__ void k_init(const float* __restrict__ x, const float* __restrict__ Wup,
                       float* __restrict__ v, float* __restrict__ v_old,
                       float* __restrict__ xcur, int N) {
  int idx = blockIdx.x * 256 + threadIdx.x;
  if (idx >= N * 32) return;
  int n = idx >> 5, vc = idx & 31;
  float w0 = Wup[vc], w1 = Wup[32 + vc];
#pragma unroll
  for (int c = 0; c < 3; ++c) {
    float val = x[n * 6 + c] * w0 + x[n * 6 + 3 + c] * w1;
    v[idx * 3 + c] = val;
    v_old[idx * 3 + c] = val;
  }
  if (vc < 6) xcur[n * 6 + vc] = x[n * 6 + vc];
}

// ---------------- CSR build ----------------

__global__ void k_zero_i(int* __restrict__ p, int n) {
  int i = blockIdx.x * 256 + threadIdx.x;
  if (i < n) p[i] = 0;
}

__global__ void k_hist(const int* __restrict__ edst, int* __restrict__ deg, int E) {
  int e = blockIdx.x * 256 + threadIdx.x;
  if (e < E) atomicAdd(&deg[edst[e]], 1);
}

__global__ __launch_bounds__(1024) void k_scan(const int* __restrict__ deg,
                                               int* __restrict__ row_ptr,
                                               int* __restrict__ cursor, int N) {
  __shared__ int part[1024];
  int t = threadIdx.x;
  int chunk = (N + 1023) / 1024;
  int base = t * chunk;
  int sum = 0;
  for (int i = 0; i < chunk; ++i) {
    int idx = base + i;
    if (idx < N) sum += deg[idx];
  }
  part[t] = sum;
  __syncthreads();
  for (int off = 1; off < 1024; off <<= 1) {
    int val = (t >= off) ? part[t - off] : 0;
    __syncthreads();
    part[t] += val;
    __syncthreads();
  }
  int run = (t > 0) ? part[t - 1] : 0;
  for (int i = 0; i < chunk; ++i) {
    int idx = base + i;
    if (idx < N) {
      row_ptr[idx] = run;
      cursor[idx] = run;
      run += deg[idx];
    }
  }
  if (t == 1023) row_ptr[N] = part[1023];
}

__global__ void k_scatter(const int* __restrict__ esrc, const int* __restrict__ edst,
                          int* __restrict__ cursor, int* __restrict__ esrc_s,
                          int* __restrict__ edst_s, int E) {
  int e = blockIdx.x * 256 + threadIdx.x;
  if (e < E) {
    int d = edst[e];
    int p = atomicAdd(&cursor[d], 1);
    esrc_s[p] = esrc[e];
    edst_s[p] = d;
  }
}

// ---------------- fused MFMA edge kernel: wave = 16 consecutive CSR-sorted edges ----
// geometry + radial MLP + all tensor-product GEMMs in one kernel.
// msg row (bf16, stride 192): [0..95] msg_s[m], [96..191] msg_v at 96 + c*32 + m'
// wb layout (u16, per wave, 3200): hid A-layout [16][72] at 0; f [16][32] at 1600;
// then overwritten by w GEMM result [16][200]; then by final out rows.
template <bool SZERO>
__global__ __launch_bounds__(256) void k_edge_mfma(
    const float* __restrict__ xcur, const float* __restrict__ s, const float* __restrict__ v,
    const int* __restrict__ esrc_s, const int* __restrict__ edst_s,
    const u16* __restrict__ fc1L, const float* __restrict__ b1,
    const u16* __restrict__ fc2L, const u16* __restrict__ WsvL0,
    const u16* __restrict__ WsvL1, const u16* __restrict__ WvsL0,
    const u16* __restrict__ WvsL1, u16* __restrict__ msgbuf, int E) {
  __shared__ u16 wbAll[4][16 * 200];
  __shared__ float aAll[4][16][6];
  int wid = threadIdx.x >> 6, lane = threadIdx.x & 63;
  int e0 = (blockIdx.x * 4 + wid) * 16;
  if (e0 >= E) return;
  u16* wb = wbAll[wid];
  int lrow = lane & 15, lg = lane >> 4;

  // ====== geometry (4 lanes per edge, duplicated; qq==0 lane writes results) ======
  {
    int el = lane >> 2, qq = lane & 3;
    int ge = e0 + el;
    if (ge >= E) ge = E - 1;
    int gs = esrc_s[ge], gd = edst_s[ge];
    float xs[6], xd[6];
    {
      const float2* ps = (const float2*)(xcur + (size_t)gs * 6);
      const float2* pd = (const float2*)(xcur + (size_t)gd * 6);
      float2 A0 = ps[0], A1 = ps[1], A2 = ps[2];
      float2 B0 = pd[0], B1 = pd[1], B2 = pd[2];
      xs[0] = A0.x; xs[1] = A0.y; xs[2] = A1.x; xs[3] = A1.y; xs[4] = A2.x; xs[5] = A2.y;
      xd[0] = B0.x; xd[1] = B0.y; xd[2] = B1.x; xd[3] = B1.y; xd[4] = B2.x; xd[5] = B2.y;
    }
    float f[16], av[6];
#pragma unroll
    for (int i = 0; i < 2; ++i) {
      float vx = xs[3 * i + 0] - xd[3 * i + 0];
      float vy = xs[3 * i + 1] - xd[3 * i + 1];
      float vz = xs[3 * i + 2] - xd[3 * i + 2];
      float r2 = vx * vx + vy * vy + vz * vz;
      float rr = sqrtf(r2);
      float invr = 1.0f / rr;
      float th = (PI_F / 3.0f) * rr;
      float s1, c1;
      __sincosf(th, &s1, &c1);
      float twc = 2.0f * c1;
      float snm = 0.f, sn = s1;
      float fc = BESSEL_C * invr;
#pragma unroll
      for (int nn = 0; nn < 8; ++nn) {
        f[8 * i + nn] = fc * sn;
        float nx = twc * sn - snm;
        snm = sn;
        sn = nx;
      }
      float uu = (2.0f / 3.0f) * rr - 2.0f;
      float cut;
      if (uu > 0.f) cut = 0.f;
      else if (uu < -1.f) cut = 1.f;
      else cut = (1.0f - __cosf(PI_F * uu)) * 0.5f;
      float sc = cut * SQRT3 * invr;
      av[3 * i + 0] = vx * sc; av[3 * i + 1] = vy * sc; av[3 * i + 2] = vz * sc;
    }
    if (qq == 0) {
      u32* fp = (u32*)(wb + 1600 + el * 32);   // [16][32] bf16, k=16..31 zeroed
#pragma unroll
      for (int i = 0; i < 8; ++i)
        fp[i] = (u32)f2b(f[2 * i]) | ((u32)f2b(f[2 * i + 1]) << 16);
#pragma unroll
      for (int i = 8; i < 16; ++i) fp[i] = 0u;
      float* ap = aAll[wid][el];
#pragma unroll
      for (int i = 0; i < 6; ++i) ap[i] = av[i];
    }
  }
  asm volatile("s_waitcnt lgkmcnt(0)" ::: "memory");
  __builtin_amdgcn_sched_barrier(0);

  // ====== MLP: hid[16][64] = silu(f @ fc1 + b1) via 4 MFMA ======
  {
    bf16x8 fA = *(const bf16x8*)(wb + 1600 + lrow * 32 + lg * 8);
    f32x4 hp[4];
#pragma unroll
    for (int nb = 0; nb < 4; ++nb) {
      bf16x8 bB = *(const bf16x8*)(fc1L + (size_t)(lg * 64 + nb * 16 + lrow) * 8);
      f32x4 z = {0.f, 0.f, 0.f, 0.f};
      hp[nb] = mfma16(fA, bB, z);
    }
#pragma unroll
    for (int nb = 0; nb < 4; ++nb) {
      float bias = b1[nb * 16 + lrow];
#pragma unroll
      for (int r = 0; r < 4; ++r) {
        float xv = hp[nb][r] + bias;
        float hv = xv * (1.0f / (1.0f + __expf(-xv)));
        wb[(4 * lg + r) * 72 + nb * 16 + lrow] = f2b(hv);   // hid[row=edge][col]
      }
    }
  }
  asm volatile("s_waitcnt lgkmcnt(0)" ::: "memory");
  __builtin_amdgcn_sched_barrier(0);

  int prow = e0 + lrow;
  if (prow >= E) prow = E - 1;

  // hid A-fragments (stride 72 u16 -> conflict-floor LDS reads)
  bf16x8 ha = *(const bf16x8*)(wb + lrow * 72 + lg * 8);
  bf16x8 hbf = *(const bf16x8*)(wb + lrow * 72 + 32 + lg * 8);
  asm volatile("s_waitcnt lgkmcnt(0)" ::: "memory");   // reads done before wb overwrite

  // ---- GEMM2: w[16,192] = hid[16,64] @ fc2[64,192], store bf16 to LDS permuted
#pragma unroll
  for (int nb = (SZERO ? 8 : 0); nb < 12; ++nb) {
    bf16x8 b0 = *(const bf16x8*)(fc2L + (size_t)(lg * 192 + nb * 16 + lrow) * 8);
    bf16x8 b1v = *(const bf16x8*)(fc2L + (size_t)((4 + lg) * 192 + nb * 16 + lrow) * 8);
    f32x4 c = {0.f, 0.f, 0.f, 0.f};
    c = mfma16(ha, b0, c);
    c = mfma16(hbf, b1v, c);
    int n = nb * 16 + lrow;
    int pn = (n < 128) ? ((n & 1) * 64 + (n >> 1)) : (128 + (n & 1) * 32 + ((n - 128) >> 1));
    int rbase = 4 * lg * 200 + pn;
    wb[rbase] = f2b(c[0]);
    wb[rbase + 200] = f2b(c[1]);
    wb[rbase + 400] = f2b(c[2]);
    wb[rbase + 600] = f2b(c[3]);
  }
  asm volatile("s_waitcnt lgkmcnt(0)" ::: "memory");

  int src = esrc_s[prow];
  const u16* wrow = wb + lrow * 200;

  // ---- Q path: T_k = s_src (.) w1_k ; Q_k = T_k @ W_sv_k
  f32x4 q0[2], q1[2];
  if (!SZERO) {
    const float* sp = s + (size_t)src * 64;
    float sv0[8], sv1[8];
    *(f32x4*)(sv0) = *(const f32x4*)(sp + lg * 8);
    *(f32x4*)(sv0 + 4) = *(const f32x4*)(sp + lg * 8 + 4);
    *(f32x4*)(sv1) = *(const f32x4*)(sp + 32 + lg * 8);
    *(f32x4*)(sv1 + 4) = *(const f32x4*)(sp + 32 + lg * 8 + 4);
    bf16x8 w0a = *(const bf16x8*)(wrow + lg * 8);
    bf16x8 w0b = *(const bf16x8*)(wrow + 32 + lg * 8);
    bf16x8 w1a = *(const bf16x8*)(wrow + 64 + lg * 8);
    bf16x8 w1b = *(const bf16x8*)(wrow + 96 + lg * 8);
    bf16x8 t0a, t0b, t1a, t1b;
#pragma unroll
    for (int j = 0; j < 8; ++j) {
      t0a[j] = (short)f2b(sv0[j] * b2f((u16)w0a[j]));
      t0b[j] = (short)f2b(sv1[j] * b2f((u16)w0b[j]));
      t1a[j] = (short)f2b(sv0[j] * b2f((u16)w1a[j]));
      t1b[j] = (short)f2b(sv1[j] * b2f((u16)w1b[j]));
    }
#pragma unroll
    for (int nb = 0; nb < 2; ++nb) {
      bf16x8 bA = *(const bf16x8*)(WsvL0 + (size_t)(lg * 32 + nb * 16 + lrow) * 8);
      bf16x8 bB = *(const bf16x8*)(WsvL0 + (size_t)((4 + lg) * 32 + nb * 16 + lrow) * 8);
      f32x4 c = {0.f, 0.f, 0.f, 0.f};
      c = mfma16(t0a, bA, c);
      c = mfma16(t0b, bB, c);
      q0[nb] = c;
      bf16x8 bC = *(const bf16x8*)(WsvL1 + (size_t)(lg * 32 + nb * 16 + lrow) * 8);
      bf16x8 bD = *(const bf16x8*)(WsvL1 + (size_t)((4 + lg) * 32 + nb * 16 + lrow) * 8);
      f32x4 c2 = {0.f, 0.f, 0.f, 0.f};
      c2 = mfma16(t1a, bC, c2);
      c2 = mfma16(t1b, bD, c2);
      q1[nb] = c2;
    }
  }

  // ---- M path: G_k = (v_src . a_k) (.) w2_k ; msg_s = G_0 @ Wvs_0 + G_1 @ Wvs_1
  float a00, a01, a02, a10, a11, a12;
  {
    const float* ap = aAll[wid][lrow];
    a00 = ap[0]; a01 = ap[1]; a02 = ap[2]; a10 = ap[3]; a11 = ap[4]; a12 = ap[5];
  }
  float vl[24];
  {
    const float* vp = v + (size_t)src * 96 + lg * 24;
#pragma unroll
    for (int i = 0; i < 6; ++i) *(f32x4*)(vl + 4 * i) = *(const f32x4*)(vp + 4 * i);
  }
  bf16x8 w2a = *(const bf16x8*)(wrow + 128 + lg * 8);
  bf16x8 w2b = *(const bf16x8*)(wrow + 160 + lg * 8);
  bf16x8 ga, gb;
#pragma unroll
  for (int j = 0; j < 8; ++j) {
    float vx = vl[3 * j], vy = vl[3 * j + 1], vz = vl[3 * j + 2];
    float d0 = vx * a00 + vy * a01 + vz * a02;
    float d1 = vx * a10 + vy * a11 + vz * a12;
    ga[j] = (short)f2b(d0 * b2f((u16)w2a[j]));
    gb[j] = (short)f2b(d1 * b2f((u16)w2b[j]));
  }
  f32x4 mS[6];
#pragma unroll
  for (int nb = 0; nb < 6; ++nb) {
    bf16x8 b0 = *(const bf16x8*)(WvsL0 + (size_t)(lg * 96 + nb * 16 + lrow) * 8);
    bf16x8 b1v = *(const bf16x8*)(WvsL1 + (size_t)(lg * 96 + nb * 16 + lrow) * 8);
    f32x4 c = {0.f, 0.f, 0.f, 0.f};
    c = mfma16(ga, b0, c);
    c = mfma16(gb, b1v, c);
    mS[nb] = c;
  }

  // ---- stage final msg rows into wb (overwrite w; all wb reads already consumed)
  asm volatile("s_waitcnt lgkmcnt(0)" ::: "memory");
#pragma unroll
  for (int nb = 0; nb < 6; ++nb) {
#pragma unroll
    for (int r = 0; r < 4; ++r)
      wb[(4 * lg + r) * 200 + nb * 16 + lrow] = f2b(mS[nb][r]);
  }
  if (!SZERO) {
#pragma unroll
    for (int nb = 0; nb < 2; ++nb) {
#pragma unroll
      for (int r = 0; r < 4; ++r) {
        int el = 4 * lg + r;
        const float* ap = aAll[wid][el];
        float Q0v = q0[nb][r], Q1v = q1[nb][r];
#pragma unroll
        for (int c = 0; c < 3; ++c)
          wb[el * 200 + 96 + c * 32 + nb * 16 + lrow] = f2b(Q0v * ap[c] + Q1v * ap[3 + c]);
      }
    }
  }
  asm volatile("s_waitcnt lgkmcnt(0)" ::: "memory");

  // ---- cooperative coalesced write: 16 consecutive rows x 192 u16
  int orow = lane >> 2, oq = lane & 3;
  if (e0 + orow < E) {
    u16* gdst = msgbuf + (size_t)(e0 + orow) * 192;
    const int NIT = SZERO ? 3 : 6;
#pragma unroll
    for (int it = 0; it < NIT; ++it) {
      int col = oq * 8 + it * 32;
      i32x4 d = *(const i32x4*)(wb + orow * 200 + col);
      *(i32x4*)(gdst + col) = d;
    }
  }
}

// ---------------- fused gather + node update ----------------
template <bool SZERO>
__global__ __launch_bounds__(128) void k_gnode(
    const u16* __restrict__ msg, const int* __restrict__ row_ptr,
    float* __restrict__ s, float* __restrict__ sold, float* __restrict__ v,
    float* __restrict__ vold,
    const float* __restrict__ Amat, const float* __restrict__ Bmat,
    const float* __restrict__ Ws, const float* __restrict__ Wv,
    const float* __restrict__ Wproj, const int* __restrict__ nattr,
    const float* __restrict__ hArr, const float* __restrict__ mixArr, int layer,
    float* __restrict__ xout, int N) {
  int n = blockIdx.x;
  int t = threadIdx.x;
  __shared__ float agg[192];   // [0..95]=agg_s[m]; [96..191]=agg_v at 96+c*32+vch
  __shared__ float srow[64];
  __shared__ float vrow[96];
  __shared__ float gateS[32];
  __shared__ float vnewS[96];
  int start = row_ptr[n], end = row_ptr[n + 1];
  int nacc = SZERO ? 48 : 96;
  if (t < nacc) {
    const u16* mp = msg + (size_t)t * 2;
    float l0 = 0.f, h0 = 0.f, l1 = 0.f, h1 = 0.f;
    float l2 = 0.f, h2 = 0.f, l3 = 0.f, h3 = 0.f;
    int p = start;
    for (; p + 4 <= end; p += 4) {
      u32 w0 = *(const u32*)(mp + (size_t)p * 192);
      u32 w1 = *(const u32*)(mp + (size_t)(p + 1) * 192);
      u32 w2 = *(const u32*)(mp + (size_t)(p + 2) * 192);
      u32 w3 = *(const u32*)(mp + (size_t)(p + 3) * 192);
      l0 += b2f((u16)w0); h0 += b2f((u16)(w0 >> 16));
      l1 += b2f((u16)w1); h1 += b2f((u16)(w1 >> 16));
      l2 += b2f((u16)w2); h2 += b2f((u16)(w2 >> 16));
      l3 += b2f((u16)w3); h3 += b2f((u16)(w3 >> 16));
    }
    for (; p < end; ++p) {
      u32 w = *(const u32*)(mp + (size_t)p * 192);
      l0 += b2f((u16)w); h0 += b2f((u16)(w >> 16));
    }
    agg[2 * t] = (l0 + l1 + l2 + l3) * INV_SQRT_NN;
    agg[2 * t + 1] = (h0 + h1 + h2 + h3) * INV_SQRT_NN;
  }
  if (SZERO && t >= 48 && t < 96) {
    agg[2 * t] = 0.f;
    agg[2 * t + 1] = 0.f;
  }
  if (t < 64) srow[t] = s[(size_t)n * 64 + t];
  if (t < 96) vrow[t] = v[(size_t)n * 96 + t];
  __syncthreads();
  int type = nattr[n];
  float hv = hArr[layer];
  float h2v = hv * hv;
  float mx = mixArr[layer];
  float cs = 0.f;
  if (t < 96) {
    cs = agg[t];
    const float* Ac = Amat + (size_t)type * 64 * 96 + t;
#pragma unroll 8
    for (int u = 0; u < 64; ++u) cs += srow[u] * Ac[u * 96];
  }
  if (t >= 64 && t < 96) gateS[t - 64] = 1.0f / (1.0f + __expf(-cs));
  __syncthreads();
  if (t < 64) {
    float gs = cs * (1.0f / (1.0f + __expf(-cs)));
    float sis = 0.f;
#pragma unroll 8
    for (int u = 0; u < 64; ++u) sis += srow[u] * Ws[u * 64 + t];
    float scur = srow[t];
    float sprev = sold[(size_t)n * 64 + t];
    float snew = 2.f * scur - sprev + h2v * (mx * gs + (mx - 1.f) * sis);
    sold[(size_t)n * 64 + t] = scur;
    s[(size_t)n * 64 + t] = snew;
  }
  if (t < 96) {
    int vch = t / 3, c = t - vch * 3;
    float cv = agg[96 + c * 32 + vch];
    const float* Bc = Bmat + (size_t)type * 1024 + vch;
    float scv = 0.f, siv = 0.f;
#pragma unroll 8
    for (int u = 0; u < 32; ++u) {
      float vu = vrow[u * 3 + c];
      scv += vu * Bc[u * 32];
      siv += vu * Wv[u * 32 + vch];
    }
    cv += scv;
    float gv = cv * gateS[vch];
    float vcur = vrow[t];
    float vprev = vold[(size_t)n * 96 + t];
    float vnew = 2.f * vcur - vprev + h2v * (mx * gv + (mx - 1.f) * siv);
    vold[(size_t)n * 96 + t] = vcur;
    v[(size_t)n * 96 + t] = vnew;
    vnewS[t] = vnew;
  }
  __syncthreads();
  if (t < 6) {
    int i = t / 3, c = t - i * 3;
    float acc = 0.f;
#pragma unroll
    for (int vo = 0; vo < 32; ++vo) acc += vnewS[vo * 3 + c] * Wproj[vo * 2 + i];
    xout[(size_t)n * 6 + t] = acc;
  }
}

extern "C" void kernel_launch(void* const* d_in, const int* in_sizes, int n_in,
                              void* d_out, int out_size, void* d_ws, size_t ws_size,
                              hipStream_t stream) {
  const float* x = (const float*)d_in[0];
  const float* emb = (const float*)d_in[1];
  const float* Wup = (const float*)d_in[2];
  const float* Wproj = (const float*)d_in[3];
  const float* fc1 = (const float*)d_in[4];
  const float* b1 = (const float*)d_in[5];
  const float* fc2 = (const float*)d_in[6];
  const float* Wsv = (const float*)d_in[7];
  const float* Wvs = (const float*)d_in[8];
  const float* Wscs = (const float*)d_in[9];
  const float* Wscv = (const float*)d_in[10];
  const float* Ws = (const float*)d_in[11];
  const float* Wv = (const float*)d_in[12];
  const float* hArr = (const float*)d_in[13];
  const float* mixArr = (const float*)d_in[14];
  const int* nattr = (const int*)d_in[15];
  const int* esrc = (const int*)d_in[16];
  const int* edst = (const int*)d_in[17];

  const int N = in_sizes[0] / 6;
  const int E = in_sizes[16];

  float* ws = (float*)d_ws;
  size_t off = 0;
  auto alloc = [&](size_t nf) {
    float* p = ws + off;
    off += (nf + 3) & ~(size_t)3;
    return p;
  };
  float* sbuf = alloc((size_t)N * 64);
  float* sold = alloc((size_t)N * 64);
  float* vbuf = alloc((size_t)N * 96);
  float* vold = alloc((size_t)N * 96);
  float* xcur = alloc((size_t)N * 6);
  float* Amat = alloc((size_t)cL * cNT * 64 * 96);
  float* Bmat = alloc((size_t)cL * cNT * 32 * 32);
  u16* fc2L = (u16*)alloc((size_t)cL * 6144);       // L*12288 bf16
  u16* WsvL = (u16*)alloc((size_t)cL * 2048);       // L*2*2048 bf16
  u16* WvsL = (u16*)alloc((size_t)cL * 3072);       // L*2*3072 bf16
  u16* fc1L = (u16*)alloc((size_t)cL * 1024);       // L*2048 bf16 (kq padded to 4)
  int* deg = (int*)alloc((size_t)(N + 4));
  int* row_ptr = (int*)alloc((size_t)(N + 4));
  int* cursor = (int*)alloc((size_t)(N + 4));
  int* esrc_s = (int*)alloc((size_t)E);
  int* edst_s = (int*)alloc((size_t)E);
  u16* msgbuf = (u16*)alloc((size_t)E * 96);        // E*192 bf16

  // init
  hipMemsetAsync(sbuf, 0, sizeof(float) * (size_t)N * 128, stream);  // sbuf + sold
  k_init<<<(N * 32 + 255) / 256, 256, 0, stream>>>(x, Wup, vbuf, vold, xcur, N);
  k_precompA<<<(cL * cNT * 64 * 96 + 255) / 256, 256, 0, stream>>>(emb, Wscs, Amat);
  k_precompB<<<(cL * cNT * 32 * 32 + 255) / 256, 256, 0, stream>>>(emb, Wscv, Bmat);
  {
    int tot = cL * 12288 + cL * 4096 + cL * 6144 + cL * 2048;
    k_packB<<<(tot + 255) / 256, 256, 0, stream>>>(fc2, Wsv, Wvs, fc1, fc2L, WsvL, WvsL, fc1L);
  }
  k_zero_i<<<(N + 255) / 256, 256, 0, stream>>>(deg, N);
  k_hist<<<(E + 255) / 256, 256, 0, stream>>>(edst, deg, E);
  k_scan<<<1, 1024, 0, stream>>>(deg, row_ptr, cursor, N);
  k_scatter<<<(E + 255) / 256, 256, 0, stream>>>(esrc, edst, cursor, esrc_s, edst_s, E);

  int eblocks = ((E + 15) / 16 + 3) / 4;
  for (int l = 0; l < cL; ++l) {
    if (l == 0)
      k_edge_mfma<true><<<eblocks, 256, 0, stream>>>(
          xcur, sbuf, vbuf, esrc_s, edst_s, fc1L + l * 2048, b1 + l * 64,
          fc2L + l * 12288, WsvL + l * 4096, WsvL + l * 4096 + 2048,
          WvsL + l * 6144, WvsL + l * 6144 + 3072, msgbuf, E);
    else
      k_edge_mfma<false><<<eblocks, 256, 0, stream>>>(
          xcur, sbuf, vbuf, esrc_s, edst_s, fc1L + l * 2048, b1 + l * 64,
          fc2L + l * 12288, WsvL + l * 4096, WsvL + l * 4096 + 2048,
          WvsL + l * 6144, WvsL + l * 6144 + 3072, msgbuf, E);
    float* xout = (l == cL - 1) ? (float*)d_out : xcur;
    if (l == 0)
      k_gnode<true><<<N, 128, 0, stream>>>(
          msgbuf, row_ptr, sbuf, sold, vbuf, vold, Amat + (size_t)l * cNT * 64 * 96,
          Bmat + (size_t)l * cNT * 1024, Ws + l * 4096, Wv + l * 1024, Wproj, nattr,
          hArr, mixArr, l, xout, N);
    else
      k_gnode<false><<<N, 128, 0, stream>>>(
          msgbuf, row_ptr, sbuf, sold, vbuf, vold, Amat + (size_t)l * cNT * 64 * 96,
          Bmat + (size_t)l * cNT * 1024, Ws + l * 4096, Wv + l * 1024, Wproj, nattr,
          hArr, mixArr, l, xout, N);
  }
}

// Round 8
// 540.258 us; speedup vs baseline: 10.8460x; 1.0329x over previous
//
#include <hip/hip_runtime.h>
#include <math.h>

constexpr int cNS = 64, cNV = 32, cNB = 8, cL = 4, cEMB = 32, cNT = 10;
constexpr float PI_F = 3.14159265358979323846f;
constexpr float INV_SQRT_NN = 0.17677669529663687f;   // 1/sqrt(32)
constexpr float BESSEL_C = 2.3094010767585034f;       // sqrt(2/3)*sqrt(8)
constexpr float SQRT3 = 1.7320508075688772f;

typedef unsigned short u16;
typedef unsigned int u32;
typedef __attribute__((ext_vector_type(8))) short bf16x8;
typedef __attribute__((ext_vector_type(4))) float f32x4;
typedef __attribute__((ext_vector_type(2))) float f32x2;
typedef __attribute__((ext_vector_type(4))) int i32x4;

__device__ __forceinline__ u16 f2b(float x) {   // f32 -> bf16 RNE (scalar fallback)
  u32 u = __float_as_uint(x);
  return (u16)((u + 0x7fffu + ((u >> 16) & 1u)) >> 16);
}
__device__ __forceinline__ float b2f(u16 h) { return __uint_as_float(((u32)h) << 16); }
__device__ __forceinline__ float blo(u32 w) { return __uint_as_float(w << 16); }
__device__ __forceinline__ float bhi(u32 w) { return __uint_as_float(w & 0xffff0000u); }

// HW packed f32->bf16 (2 values, 1 instruction)
__device__ __forceinline__ u32 pkbf(float lo, float hi) {
  u32 r;
  asm("v_cvt_pk_bf16_f32 %0, %1, %2" : "=v"(r) : "v"(lo), "v"(hi));
  return r;
}

union U8 { bf16x8 v; u32 w[4]; };

__device__ __forceinline__ f32x4 mfma16(bf16x8 a, bf16x8 b, f32x4 c) {
  return __builtin_amdgcn_mfma_f32_16x16x32_bf16(a, b, c, 0, 0, 0);
}

// ---------------- precompute kernels ----------------

__global__ void k_precompA(const float* __restrict__ emb, const float* __restrict__ Wss,
                           float* __restrict__ A) {
  int idx = blockIdx.x * 256 + threadIdx.x;
  if (idx >= cL * cNT * 64 * 96) return;
  int m = idx % 96;
  int u = (idx / 96) % 64;
  int t = (idx / (96 * 64)) % cNT;
  int l = idx / (96 * 64 * cNT);
  float acc = 0.f;
#pragma unroll
  for (int e = 0; e < 32; ++e)
    acc += emb[t * 32 + e] * Wss[((size_t)(l * 64 + u) * 32 + e) * 96 + m];
  A[idx] = acc;
}

__global__ void k_precompB(const float* __restrict__ emb, const float* __restrict__ Wsv_,
                           float* __restrict__ B) {
  int idx = blockIdx.x * 256 + threadIdx.x;
  if (idx >= cL * cNT * 32 * 32) return;
  int vo = idx % 32;
  int u = (idx / 32) % 32;
  int t = (idx / 1024) % cNT;
  int l = idx / (1024 * cNT);
  float acc = 0.f;
#pragma unroll
  for (int e = 0; e < 32; ++e)
    acc += emb[t * 32 + e] * Wsv_[((size_t)(l * 32 + u) * 32 + e) * 32 + vo];
  B[idx] = acc;
}

// pack fc2 / W_sv / W_vs / fc1 into bf16 MFMA-B layouts: BL[(k/8)*N*8 + n*8 + (k%8)]
__global__ void k_packB(const float* __restrict__ fc2, const float* __restrict__ Wsv,
                        const float* __restrict__ Wvs, const float* __restrict__ fc1,
                        u16* __restrict__ fc2L, u16* __restrict__ WsvL,
                        u16* __restrict__ WvsL, u16* __restrict__ fc1L) {
  int idx = blockIdx.x * 256 + threadIdx.x;
  const int T1 = cL * 12288, T2 = cL * 2 * 2048, T3 = cL * 2 * 3072, T4 = cL * 2048;
  if (idx < T1) {
    int l = idx / 12288, r = idx % 12288;
    int ki = r & 7, tt = r >> 3;
    int nn = tt % 192, kq = tt / 192;
    fc2L[idx] = f2b(fc2[((size_t)(l * 64) + kq * 8 + ki) * 192 + nn]);
  } else if (idx < T1 + T2) {
    int r0 = idx - T1;
    int l = r0 / 4096, r1 = r0 % 4096;
    int k2 = r1 / 2048, r = r1 % 2048;
    int ki = r & 7, tt = r >> 3;
    int mm = tt % 32, kq = tt / 32;
    WsvL[r0] = f2b(Wsv[((size_t)((l * 64 + kq * 8 + ki) * 2) + k2) * 32 + mm]);
  } else if (idx < T1 + T2 + T3) {
    int r0 = idx - T1 - T2;
    int l = r0 / 6144, r1 = r0 % 6144;
    int k2 = r1 / 3072, r = r1 % 3072;
    int ki = r & 7, tt = r >> 3;
    int mm = tt % 96, kq = tt / 96;
    WvsL[r0] = f2b(Wvs[((size_t)((l * 32 + kq * 8 + ki) * 2) + k2) * 96 + mm]);
  } else if (idx < T1 + T2 + T3 + T4) {
    int r0 = idx - T1 - T2 - T3;
    int l = r0 / 2048, r1 = r0 % 2048;
    int kq = r1 / 512, rem = r1 % 512;
    int n = rem / 8, ki = rem & 7;
    fc1L[r0] = (kq < 2) ? f2b(fc1[l * 1024 + (kq * 8 + ki) * 64 + n]) : (u16)0;
  }
}

__global__ void k_init(const float* __restrict__ x, const float* __restrict__ Wup,
                       float* __restrict__ v, float* __restrict__ v_old,
                       float* __restrict__ xcur, int N) {
  int idx = blockIdx.x * 256 + threadIdx.x;
  if (idx >= N * 32) return;
  int n = idx >> 5, vc = idx & 31;
  float w0 = Wup[vc], w1 = Wup[32 + vc];
#pragma unroll
  for (int c = 0; c < 3; ++c) {
    float val = x[n * 6 + c] * w0 + x[n * 6 + 3 + c] * w1;
    v[idx * 3 + c] = val;
    v_old[idx * 3 + c] = val;
  }
  if (vc < 6) xcur[n * 6 + vc] = x[n * 6 + vc];
}

// ---------------- CSR build ----------------

__global__ void k_zero_i(int* __restrict__ p, int n) {
  int i = blockIdx.x * 256 + threadIdx.x;
  if (i < n) p[i] = 0;
}

__global__ void k_hist(const int* __restrict__ edst, int* __restrict__ deg, int E) {
  int e = blockIdx.x * 256 + threadIdx.x;
  if (e < E) atomicAdd(&deg[edst[e]], 1);
}

__global__ __launch_bounds__(1024) void k_scan(const int* __restrict__ deg,
                                               int* __restrict__ row_ptr,
                                               int* __restrict__ cursor, int N) {
  __shared__ int part[1024];
  int t = threadIdx.x;
  int chunk = (N + 1023) / 1024;
  int base = t * chunk;
  int sum = 0;
  for (int i = 0; i < chunk; ++i) {
    int idx = base + i;
    if (idx < N) sum += deg[idx];
  }
  part[t] = sum;
  __syncthreads();
  for (int off = 1; off < 1024; off <<= 1) {
    int val = (t >= off) ? part[t - off] : 0;
    __syncthreads();
    part[t] += val;
    __syncthreads();
  }
  int run = (t > 0) ? part[t - 1] : 0;
  for (int i = 0; i < chunk; ++i) {
    int idx = base + i;
    if (idx < N) {
      row_ptr[idx] = run;
      cursor[idx] = run;
      run += deg[idx];
    }
  }
  if (t == 1023) row_ptr[N] = part[1023];
}

__global__ void k_scatter(const int* __restrict__ esrc, const int* __restrict__ edst,
                          int* __restrict__ cursor, int* __restrict__ esrc_s,
                          int* __restrict__ edst_s, int E) {
  int e = blockIdx.x * 256 + threadIdx.x;
  if (e < E) {
    int d = edst[e];
    int p = atomicAdd(&cursor[d], 1);
    esrc_s[p] = esrc[e];
    edst_s[p] = d;
  }
}

// ---------------- fused MFMA edge kernel: wave = 16 consecutive CSR-sorted edges ----
// msg row (bf16): SZERO stride 96: [0..95] msg_s; else stride 192: + msg_v at 96+c*32+m'
template <bool SZERO>
__global__ __launch_bounds__(256) void k_edge_mfma(
    const float* __restrict__ xcur, const float* __restrict__ s, const float* __restrict__ v,
    const int* __restrict__ esrc_s, const int* __restrict__ edst_s,
    const u16* __restrict__ fc1L, const float* __restrict__ b1,
    const u16* __restrict__ fc2L, const u16* __restrict__ WsvL0,
    const u16* __restrict__ WsvL1, const u16* __restrict__ WvsL0,
    const u16* __restrict__ WvsL1, u16* __restrict__ msgbuf, int E) {
  __shared__ u16 wbAll[4][16 * 200];
  __shared__ float aAll[4][16][6];
  int wid = threadIdx.x >> 6, lane = threadIdx.x & 63;
  int e0 = (blockIdx.x * 4 + wid) * 16;
  if (e0 >= E) return;
  u16* wb = wbAll[wid];
  int lrow = lane & 15, lg = lane >> 4;

  // ====== geometry (4 lanes per edge, duplicated; qq==0 lane writes results) ======
  {
    int el = lane >> 2, qq = lane & 3;
    int ge = e0 + el;
    if (ge >= E) ge = E - 1;
    int gs = esrc_s[ge], gd = edst_s[ge];
    float xs[6], xd[6];
    {
      const float2* ps = (const float2*)(xcur + (size_t)gs * 6);
      const float2* pd = (const float2*)(xcur + (size_t)gd * 6);
      float2 A0 = ps[0], A1 = ps[1], A2 = ps[2];
      float2 B0 = pd[0], B1 = pd[1], B2 = pd[2];
      xs[0] = A0.x; xs[1] = A0.y; xs[2] = A1.x; xs[3] = A1.y; xs[4] = A2.x; xs[5] = A2.y;
      xd[0] = B0.x; xd[1] = B0.y; xd[2] = B1.x; xd[3] = B1.y; xd[4] = B2.x; xd[5] = B2.y;
    }
    float f[16], av[6];
#pragma unroll
    for (int i = 0; i < 2; ++i) {
      float vx = xs[3 * i + 0] - xd[3 * i + 0];
      float vy = xs[3 * i + 1] - xd[3 * i + 1];
      float vz = xs[3 * i + 2] - xd[3 * i + 2];
      float r2 = vx * vx + vy * vy + vz * vz;
      float rr = sqrtf(r2);
      float invr = 1.0f / rr;
      float th = (PI_F / 3.0f) * rr;
      float s1, c1;
      __sincosf(th, &s1, &c1);
      float twc = 2.0f * c1;
      float snm = 0.f, sn = s1;
      float fc = BESSEL_C * invr;
#pragma unroll
      for (int nn = 0; nn < 8; ++nn) {
        f[8 * i + nn] = fc * sn;
        float nx = twc * sn - snm;
        snm = sn;
        sn = nx;
      }
      float uu = (2.0f / 3.0f) * rr - 2.0f;
      float cut;
      if (uu > 0.f) cut = 0.f;
      else if (uu < -1.f) cut = 1.f;
      else cut = (1.0f - __cosf(PI_F * uu)) * 0.5f;
      float sc = cut * SQRT3 * invr;
      av[3 * i + 0] = vx * sc; av[3 * i + 1] = vy * sc; av[3 * i + 2] = vz * sc;
    }
    if (qq == 0) {
      u32* fp = (u32*)(wb + 1600 + el * 32);   // [16][32] bf16, k=16..31 zeroed
#pragma unroll
      for (int i = 0; i < 8; ++i) fp[i] = pkbf(f[2 * i], f[2 * i + 1]);
#pragma unroll
      for (int i = 8; i < 16; ++i) fp[i] = 0u;
      float* ap = aAll[wid][el];
#pragma unroll
      for (int i = 0; i < 6; ++i) ap[i] = av[i];
    }
  }
  asm volatile("s_waitcnt lgkmcnt(0)" ::: "memory");
  __builtin_amdgcn_sched_barrier(0);

  // ====== MLP: hid[16][64] = silu(f @ fc1 + b1) via 4 MFMA ======
  {
    bf16x8 fA = *(const bf16x8*)(wb + 1600 + lrow * 32 + lg * 8);
    f32x4 hp[4];
#pragma unroll
    for (int nb = 0; nb < 4; ++nb) {
      bf16x8 bB = *(const bf16x8*)(fc1L + (size_t)(lg * 64 + nb * 16 + lrow) * 8);
      f32x4 z = {0.f, 0.f, 0.f, 0.f};
      hp[nb] = mfma16(fA, bB, z);
    }
#pragma unroll
    for (int nb = 0; nb < 4; ++nb) {
      float bias = b1[nb * 16 + lrow];
      float hv[4];
#pragma unroll
      for (int r = 0; r < 4; ++r) {
        float xv = hp[nb][r] + bias;
        hv[r] = xv * (1.0f / (1.0f + __expf(-xv)));
      }
      u32 p01 = pkbf(hv[0], hv[1]);
      u32 p23 = pkbf(hv[2], hv[3]);
      int col = nb * 16 + lrow;
      wb[(4 * lg + 0) * 72 + col] = (u16)p01;
      wb[(4 * lg + 1) * 72 + col] = (u16)(p01 >> 16);
      wb[(4 * lg + 2) * 72 + col] = (u16)p23;
      wb[(4 * lg + 3) * 72 + col] = (u16)(p23 >> 16);
    }
  }
  asm volatile("s_waitcnt lgkmcnt(0)" ::: "memory");
  __builtin_amdgcn_sched_barrier(0);

  int prow = e0 + lrow;
  if (prow >= E) prow = E - 1;

  // hid A-fragments
  bf16x8 ha = *(const bf16x8*)(wb + lrow * 72 + lg * 8);
  bf16x8 hbf = *(const bf16x8*)(wb + lrow * 72 + 32 + lg * 8);
  asm volatile("s_waitcnt lgkmcnt(0)" ::: "memory");   // reads done before wb overwrite

  // ---- GEMM2: w[16,192] = hid[16,64] @ fc2[64,192], store bf16 to LDS permuted
#pragma unroll
  for (int nb = (SZERO ? 8 : 0); nb < 12; ++nb) {
    bf16x8 b0 = *(const bf16x8*)(fc2L + (size_t)(lg * 192 + nb * 16 + lrow) * 8);
    bf16x8 b1v = *(const bf16x8*)(fc2L + (size_t)((4 + lg) * 192 + nb * 16 + lrow) * 8);
    f32x4 c = {0.f, 0.f, 0.f, 0.f};
    c = mfma16(ha, b0, c);
    c = mfma16(hbf, b1v, c);
    int n = nb * 16 + lrow;
    int pn = (n < 128) ? ((n & 1) * 64 + (n >> 1)) : (128 + (n & 1) * 32 + ((n - 128) >> 1));
    int rbase = 4 * lg * 200 + pn;
    u32 p01 = pkbf(c[0], c[1]);
    u32 p23 = pkbf(c[2], c[3]);
    wb[rbase] = (u16)p01;
    wb[rbase + 200] = (u16)(p01 >> 16);
    wb[rbase + 400] = (u16)p23;
    wb[rbase + 600] = (u16)(p23 >> 16);
  }
  asm volatile("s_waitcnt lgkmcnt(0)" ::: "memory");

  int src = esrc_s[prow];
  const u16* wrow = wb + lrow * 200;

  // ---- Q path: T_k = s_src (.) w1_k ; Q_k = T_k @ W_sv_k
  f32x4 q0[2], q1[2];
  if (!SZERO) {
    const float* sp = s + (size_t)src * 64;
    float sv0[8], sv1[8];
    *(f32x4*)(sv0) = *(const f32x4*)(sp + lg * 8);
    *(f32x4*)(sv0 + 4) = *(const f32x4*)(sp + lg * 8 + 4);
    *(f32x4*)(sv1) = *(const f32x4*)(sp + 32 + lg * 8);
    *(f32x4*)(sv1 + 4) = *(const f32x4*)(sp + 32 + lg * 8 + 4);
    i32x4 W0a = *(const i32x4*)(wrow + lg * 8);
    i32x4 W0b = *(const i32x4*)(wrow + 32 + lg * 8);
    i32x4 W1a = *(const i32x4*)(wrow + 64 + lg * 8);
    i32x4 W1b = *(const i32x4*)(wrow + 96 + lg * 8);
    U8 t0a, t0b, t1a, t1b;
#pragma unroll
    for (int j2 = 0; j2 < 4; ++j2) {
      u32 wa = (u32)W0a[j2], wbv = (u32)W0b[j2], wc = (u32)W1a[j2], wd = (u32)W1b[j2];
      t0a.w[j2] = pkbf(sv0[2 * j2] * blo(wa), sv0[2 * j2 + 1] * bhi(wa));
      t0b.w[j2] = pkbf(sv1[2 * j2] * blo(wbv), sv1[2 * j2 + 1] * bhi(wbv));
      t1a.w[j2] = pkbf(sv0[2 * j2] * blo(wc), sv0[2 * j2 + 1] * bhi(wc));
      t1b.w[j2] = pkbf(sv1[2 * j2] * blo(wd), sv1[2 * j2 + 1] * bhi(wd));
    }
#pragma unroll
    for (int nb = 0; nb < 2; ++nb) {
      bf16x8 bA = *(const bf16x8*)(WsvL0 + (size_t)(lg * 32 + nb * 16 + lrow) * 8);
      bf16x8 bB = *(const bf16x8*)(WsvL0 + (size_t)((4 + lg) * 32 + nb * 16 + lrow) * 8);
      f32x4 c = {0.f, 0.f, 0.f, 0.f};
      c = mfma16(t0a.v, bA, c);
      c = mfma16(t0b.v, bB, c);
      q0[nb] = c;
      bf16x8 bC = *(const bf16x8*)(WsvL1 + (size_t)(lg * 32 + nb * 16 + lrow) * 8);
      bf16x8 bD = *(const bf16x8*)(WsvL1 + (size_t)((4 + lg) * 32 + nb * 16 + lrow) * 8);
      f32x4 c2 = {0.f, 0.f, 0.f, 0.f};
      c2 = mfma16(t1a.v, bC, c2);
      c2 = mfma16(t1b.v, bD, c2);
      q1[nb] = c2;
    }
  }

  // ---- M path: G_k = (v_src . a_k) (.) w2_k ; msg_s = G_0 @ Wvs_0 + G_1 @ Wvs_1
  float a00, a01, a02, a10, a11, a12;
  {
    const float* ap = aAll[wid][lrow];
    a00 = ap[0]; a01 = ap[1]; a02 = ap[2]; a10 = ap[3]; a11 = ap[4]; a12 = ap[5];
  }
  float vl[24];
  {
    const float* vp = v + (size_t)src * 96 + lg * 24;
#pragma unroll
    for (int i = 0; i < 6; ++i) *(f32x4*)(vl + 4 * i) = *(const f32x4*)(vp + 4 * i);
  }
  i32x4 W2a = *(const i32x4*)(wrow + 128 + lg * 8);
  i32x4 W2b = *(const i32x4*)(wrow + 160 + lg * 8);
  U8 ga, gb;
#pragma unroll
  for (int j2 = 0; j2 < 4; ++j2) {
    float d0a, d1a, d0b, d1b;
    {
      float vx = vl[6 * j2 + 0], vy = vl[6 * j2 + 1], vz = vl[6 * j2 + 2];
      d0a = vx * a00 + vy * a01 + vz * a02;
      d1a = vx * a10 + vy * a11 + vz * a12;
    }
    {
      float vx = vl[6 * j2 + 3], vy = vl[6 * j2 + 4], vz = vl[6 * j2 + 5];
      d0b = vx * a00 + vy * a01 + vz * a02;
      d1b = vx * a10 + vy * a11 + vz * a12;
    }
    u32 wa = (u32)W2a[j2], wbv = (u32)W2b[j2];
    ga.w[j2] = pkbf(d0a * blo(wa), d0b * bhi(wa));
    gb.w[j2] = pkbf(d1a * blo(wbv), d1b * bhi(wbv));
  }
  f32x4 mS[6];
#pragma unroll
  for (int nb = 0; nb < 6; ++nb) {
    bf16x8 b0 = *(const bf16x8*)(WvsL0 + (size_t)(lg * 96 + nb * 16 + lrow) * 8);
    bf16x8 b1v = *(const bf16x8*)(WvsL1 + (size_t)(lg * 96 + nb * 16 + lrow) * 8);
    f32x4 c = {0.f, 0.f, 0.f, 0.f};
    c = mfma16(ga.v, b0, c);
    c = mfma16(gb.v, b1v, c);
    mS[nb] = c;
  }

  // ---- stage final msg rows into wb (overwrite w; all wb reads already consumed)
  asm volatile("s_waitcnt lgkmcnt(0)" ::: "memory");
#pragma unroll
  for (int nb = 0; nb < 6; ++nb) {
    u32 p01 = pkbf(mS[nb][0], mS[nb][1]);
    u32 p23 = pkbf(mS[nb][2], mS[nb][3]);
    int col = nb * 16 + lrow;
    wb[(4 * lg + 0) * 200 + col] = (u16)p01;
    wb[(4 * lg + 1) * 200 + col] = (u16)(p01 >> 16);
    wb[(4 * lg + 2) * 200 + col] = (u16)p23;
    wb[(4 * lg + 3) * 200 + col] = (u16)(p23 >> 16);
  }
  if (!SZERO) {
#pragma unroll
    for (int nb = 0; nb < 2; ++nb) {
#pragma unroll
      for (int r = 0; r < 4; ++r) {
        int el = 4 * lg + r;
        const float* ap = aAll[wid][el];
        float Q0v = q0[nb][r], Q1v = q1[nb][r];
        float v0 = Q0v * ap[0] + Q1v * ap[3];
        float v1 = Q0v * ap[1] + Q1v * ap[4];
        float v2 = Q0v * ap[2] + Q1v * ap[5];
        u32 p01 = pkbf(v0, v1);
        int base = el * 200 + 96 + nb * 16 + lrow;
        wb[base] = (u16)p01;
        wb[base + 32] = (u16)(p01 >> 16);
        wb[base + 64] = f2b(v2);
      }
    }
  }
  asm volatile("s_waitcnt lgkmcnt(0)" ::: "memory");

  // ---- cooperative coalesced write: 16 consecutive rows, stride 96 (SZERO) / 192
  int orow = lane >> 2, oq = lane & 3;
  if (e0 + orow < E) {
    const int OST = SZERO ? 96 : 192;
    u16* gdst = msgbuf + (size_t)(e0 + orow) * OST;
    const int NIT = SZERO ? 3 : 6;
#pragma unroll
    for (int it = 0; it < NIT; ++it) {
      int col = oq * 8 + it * 32;
      i32x4 d = *(const i32x4*)(wb + orow * 200 + col);
      *(i32x4*)(gdst + col) = d;
    }
  }
}

// ---------------- fused gather + node update ----------------
template <bool SZERO>
__global__ __launch_bounds__(128) void k_gnode(
    const u16* __restrict__ msg, const int* __restrict__ row_ptr,
    float* __restrict__ s, float* __restrict__ sold, float* __restrict__ v,
    float* __restrict__ vold,
    const float* __restrict__ Amat, const float* __restrict__ Bmat,
    const float* __restrict__ Ws, const float* __restrict__ Wv,
    const float* __restrict__ Wproj, const int* __restrict__ nattr,
    const float* __restrict__ hArr, const float* __restrict__ mixArr, int layer,
    float* __restrict__ xout, int N) {
  int n = blockIdx.x;
  int t = threadIdx.x;
  __shared__ float agg[192];   // [0..95]=agg_s[m]; [96..191]=agg_v at 96+c*32+vch
  __shared__ float srow[64];
  __shared__ float vrow[96];
  __shared__ float gateS[32];
  __shared__ float vnewS[96];
  int start = row_ptr[n], end = row_ptr[n + 1];
  const int STRIDE = SZERO ? 96 : 192;
  int nacc = SZERO ? 48 : 96;
  if (t < nacc) {
    const u16* mp = msg + (size_t)t * 2;
    float aL[4] = {0.f, 0.f, 0.f, 0.f}, aH[4] = {0.f, 0.f, 0.f, 0.f};
    int p = start;
    for (; p + 8 <= end; p += 8) {
      u32 w[8];
#pragma unroll
      for (int k = 0; k < 8; ++k) w[k] = *(const u32*)(mp + (size_t)(p + k) * STRIDE);
#pragma unroll
      for (int k = 0; k < 8; ++k) {
        aL[k & 3] += blo(w[k]);
        aH[k & 3] += bhi(w[k]);
      }
    }
    for (; p < end; ++p) {
      u32 w = *(const u32*)(mp + (size_t)p * STRIDE);
      aL[0] += blo(w);
      aH[0] += bhi(w);
    }
    agg[2 * t] = (aL[0] + aL[1] + aL[2] + aL[3]) * INV_SQRT_NN;
    agg[2 * t + 1] = (aH[0] + aH[1] + aH[2] + aH[3]) * INV_SQRT_NN;
  }
  if (SZERO && t >= 48 && t < 96) {
    agg[2 * t] = 0.f;
    agg[2 * t + 1] = 0.f;
  }
  if (t < 64) srow[t] = s[(size_t)n * 64 + t];
  if (t < 96) vrow[t] = v[(size_t)n * 96 + t];
  __syncthreads();
  int type = nattr[n];
  float hv = hArr[layer];
  float h2v = hv * hv;
  float mx = mixArr[layer];
  float cs = 0.f;
  if (t < 96) {
    cs = agg[t];
    const float* Ac = Amat + (size_t)type * 64 * 96 + t;
#pragma unroll 8
    for (int u = 0; u < 64; ++u) cs += srow[u] * Ac[u * 96];
  }
  if (t >= 64 && t < 96) gateS[t - 64] = 1.0f / (1.0f + __expf(-cs));
  __syncthreads();
  if (t < 64) {
    float gs = cs * (1.0f / (1.0f + __expf(-cs)));
    float sis = 0.f;
#pragma unroll 8
    for (int u = 0; u < 64; ++u) sis += srow[u] * Ws[u * 64 + t];
    float scur = srow[t];
    float sprev = sold[(size_t)n * 64 + t];
    float snew = 2.f * scur - sprev + h2v * (mx * gs + (mx - 1.f) * sis);
    sold[(size_t)n * 64 + t] = scur;
    s[(size_t)n * 64 + t] = snew;
  }
  if (t < 96) {
    int vch = t / 3, c = t - vch * 3;
    float cv = agg[96 + c * 32 + vch];
    const float* Bc = Bmat + (size_t)type * 1024 + vch;
    float scv = 0.f, siv = 0.f;
#pragma unroll 8
    for (int u = 0; u < 32; ++u) {
      float vu = vrow[u * 3 + c];
      scv += vu * Bc[u * 32];
      siv += vu * Wv[u * 32 + vch];
    }
    cv += scv;
    float gv = cv * gateS[vch];
    float vcur = vrow[t];
    float vprev = vold[(size_t)n * 96 + t];
    float vnew = 2.f * vcur - vprev + h2v * (mx * gv + (mx - 1.f) * siv);
    vold[(size_t)n * 96 + t] = vcur;
    v[(size_t)n * 96 + t] = vnew;
    vnewS[t] = vnew;
  }
  __syncthreads();
  if (t < 6) {
    int i = t / 3, c = t - i * 3;
    float acc = 0.f;
#pragma unroll
    for (int vo = 0; vo < 32; ++vo) acc += vnewS[vo * 3 + c] * Wproj[vo * 2 + i];
    xout[(size_t)n * 6 + t] = acc;
  }
}

extern "C" void kernel_launch(void* const* d_in, const int* in_sizes, int n_in,
                              void* d_out, int out_size, void* d_ws, size_t ws_size,
                              hipStream_t stream) {
  const float* x = (const float*)d_in[0];
  const float* emb = (const float*)d_in[1];
  const float* Wup = (const float*)d_in[2];
  const float* Wproj = (const float*)d_in[3];
  const float* fc1 = (const float*)d_in[4];
  const float* b1 = (const float*)d_in[5];
  const float* fc2 = (const float*)d_in[6];
  const float* Wsv = (const float*)d_in[7];
  const float* Wvs = (const float*)d_in[8];
  const float* Wscs = (const float*)d_in[9];
  const float* Wscv = (const float*)d_in[10];
  const float* Ws = (const float*)d_in[11];
  const float* Wv = (const float*)d_in[12];
  const float* hArr = (const float*)d_in[13];
  const float* mixArr = (const float*)d_in[14];
  const int* nattr = (const int*)d_in[15];
  const int* esrc = (const int*)d_in[16];
  const int* edst = (const int*)d_in[17];

  const int N = in_sizes[0] / 6;
  const int E = in_sizes[16];

  float* ws = (float*)d_ws;
  size_t off = 0;
  auto alloc = [&](size_t nf) {
    float* p = ws + off;
    off += (nf + 3) & ~(size_t)3;
    return p;
  };
  float* sbuf = alloc((size_t)N * 64);
  float* sold = alloc((size_t)N * 64);
  float* vbuf = alloc((size_t)N * 96);
  float* vold = alloc((size_t)N * 96);
  float* xcur = alloc((size_t)N * 6);
  float* Amat = alloc((size_t)cL * cNT * 64 * 96);
  float* Bmat = alloc((size_t)cL * cNT * 32 * 32);
  u16* fc2L = (u16*)alloc((size_t)cL * 6144);       // L*12288 bf16
  u16* WsvL = (u16*)alloc((size_t)cL * 2048);       // L*2*2048 bf16
  u16* WvsL = (u16*)alloc((size_t)cL * 3072);       // L*2*3072 bf16
  u16* fc1L = (u16*)alloc((size_t)cL * 1024);       // L*2048 bf16 (kq padded to 4)
  int* deg = (int*)alloc((size_t)(N + 4));
  int* row_ptr = (int*)alloc((size_t)(N + 4));
  int* cursor = (int*)alloc((size_t)(N + 4));
  int* esrc_s = (int*)alloc((size_t)E);
  int* edst_s = (int*)alloc((size_t)E);
  u16* msgbuf = (u16*)alloc((size_t)E * 96);        // E*192 bf16

  // init
  hipMemsetAsync(sbuf, 0, sizeof(float) * (size_t)N * 128, stream);  // sbuf + sold
  k_init<<<(N * 32 + 255) / 256, 256, 0, stream>>>(x, Wup, vbuf, vold, xcur, N);
  k_precompA<<<(cL * cNT * 64 * 96 + 255) / 256, 256, 0, stream>>>(emb, Wscs, Amat);
  k_precompB<<<(cL * cNT * 32 * 32 + 255) / 256, 256, 0, stream>>>(emb, Wscv, Bmat);
  {
    int tot = cL * 12288 + cL * 4096 + cL * 6144 + cL * 2048;
    k_packB<<<(tot + 255) / 256, 256, 0, stream>>>(fc2, Wsv, Wvs, fc1, fc2L, WsvL, WvsL, fc1L);
  }
  k_zero_i<<<(N + 255) / 256, 256, 0, stream>>>(deg, N);
  k_hist<<<(E + 255) / 256, 256, 0, stream>>>(edst, deg, E);
  k_scan<<<1, 1024, 0, stream>>>(deg, row_ptr, cursor, N);
  k_scatter<<<(E + 255) / 256, 256, 0, stream>>>(esrc, edst, cursor, esrc_s, edst_s, E);

  int eblocks = ((E + 15) / 16 + 3) / 4;
  for (int l = 0; l < cL; ++l) {
    if (l == 0)
      k_edge_mfma<true><<<eblocks, 256, 0, stream>>>(
          xcur, sbuf, vbuf, esrc_s, edst_s, fc1L + l * 2048, b1 + l * 64,
          fc2L + l * 12288, WsvL + l * 4096, WsvL + l * 4096 + 2048,
          WvsL + l * 6144, WvsL + l * 6144 + 3072, msgbuf, E);
    else
      k_edge_mfma<false><<<eblocks, 256, 0, stream>>>(
          xcur, sbuf, vbuf, esrc_s, edst_s, fc1L + l * 2048, b1 + l * 64,
          fc2L + l * 12288, WsvL + l * 4096, WsvL + l * 4096 + 2048,
          WvsL + l * 6144, WvsL + l * 6144 + 3072, msgbuf, E);
    float* xout = (l == cL - 1) ? (float*)d_out : xcur;
    if (l == 0)
      k_gnode<true><<<N, 128, 0, stream>>>(
          msgbuf, row_ptr, sbuf, sold, vbuf, vold, Amat + (size_t)l * cNT * 64 * 96,
          Bmat + (size_t)l * cNT * 1024, Ws + l * 4096, Wv + l * 1024, Wproj, nattr,
          hArr, mixArr, l, xout, N);
    else
      k_gnode<false><<<N, 128, 0, stream>>>(
          msgbuf, row_ptr, sbuf, sold, vbuf, vold, Amat + (size_t)l * cNT * 64 * 96,
          Bmat + (size_t)l * cNT * 1024, Ws + l * 4096, Wv + l * 1024, Wproj, nattr,
          hArr, mixArr, l, xout, N);
  }
}

// Round 9
// 539.649 us; speedup vs baseline: 10.8583x; 1.0011x over previous
//
#include <hip/hip_runtime.h>
#include <math.h>

constexpr int cNS = 64, cNV = 32, cNB = 8, cL = 4, cEMB = 32, cNT = 10;
constexpr float PI_F = 3.14159265358979323846f;
constexpr float INV_SQRT_NN = 0.17677669529663687f;   // 1/sqrt(32)
constexpr float BESSEL_C = 2.3094010767585034f;       // sqrt(2/3)*sqrt(8)
constexpr float SQRT3 = 1.7320508075688772f;

typedef unsigned short u16;
typedef unsigned int u32;
typedef __attribute__((ext_vector_type(8))) short bf16x8;
typedef __attribute__((ext_vector_type(4))) float f32x4;
typedef __attribute__((ext_vector_type(2))) float f32x2;
typedef __attribute__((ext_vector_type(4))) int i32x4;

__device__ __forceinline__ u16 f2b(float x) {   // f32 -> bf16 RNE (scalar fallback)
  u32 u = __float_as_uint(x);
  return (u16)((u + 0x7fffu + ((u >> 16) & 1u)) >> 16);
}
__device__ __forceinline__ float b2f(u16 h) { return __uint_as_float(((u32)h) << 16); }
__device__ __forceinline__ float blo(u32 w) { return __uint_as_float(w << 16); }
__device__ __forceinline__ float bhi(u32 w) { return __uint_as_float(w & 0xffff0000u); }

// HW packed f32->bf16 (2 values, 1 instruction)
__device__ __forceinline__ u32 pkbf(float lo, float hi) {
  u32 r;
  asm("v_cvt_pk_bf16_f32 %0, %1, %2" : "=v"(r) : "v"(lo), "v"(hi));
  return r;
}

union U8 { bf16x8 v; u32 w[4]; };

__device__ __forceinline__ f32x4 mfma16(bf16x8 a, bf16x8 b, f32x4 c) {
  return __builtin_amdgcn_mfma_f32_16x16x32_bf16(a, b, c, 0, 0, 0);
}

// XOR bank-swizzle for the 200-stride wb region (u16 units; byte bits 4-5)
__device__ __forceinline__ int xm200(int row) { return ((row >> 2) & 3) << 3; }

// ---------------- precompute kernels ----------------

__global__ void k_precompA(const float* __restrict__ emb, const float* __restrict__ Wss,
                           float* __restrict__ A) {
  int idx = blockIdx.x * 256 + threadIdx.x;
  if (idx >= cL * cNT * 64 * 96) return;
  int m = idx % 96;
  int u = (idx / 96) % 64;
  int t = (idx / (96 * 64)) % cNT;
  int l = idx / (96 * 64 * cNT);
  float acc = 0.f;
#pragma unroll
  for (int e = 0; e < 32; ++e)
    acc += emb[t * 32 + e] * Wss[((size_t)(l * 64 + u) * 32 + e) * 96 + m];
  A[idx] = acc;
}

__global__ void k_precompB(const float* __restrict__ emb, const float* __restrict__ Wsv_,
                           float* __restrict__ B) {
  int idx = blockIdx.x * 256 + threadIdx.x;
  if (idx >= cL * cNT * 32 * 32) return;
  int vo = idx % 32;
  int u = (idx / 32) % 32;
  int t = (idx / 1024) % cNT;
  int l = idx / (1024 * cNT);
  float acc = 0.f;
#pragma unroll
  for (int e = 0; e < 32; ++e)
    acc += emb[t * 32 + e] * Wsv_[((size_t)(l * 32 + u) * 32 + e) * 32 + vo];
  B[idx] = acc;
}

// pack fc2 / W_sv / W_vs / fc1 into bf16 MFMA-B layouts: BL[(k/8)*N*8 + n*8 + (k%8)]
__global__ void k_packB(const float* __restrict__ fc2, const float* __restrict__ Wsv,
                        const float* __restrict__ Wvs, const float* __restrict__ fc1,
                        u16* __restrict__ fc2L, u16* __restrict__ WsvL,
                        u16* __restrict__ WvsL, u16* __restrict__ fc1L) {
  int idx = blockIdx.x * 256 + threadIdx.x;
  const int T1 = cL * 12288, T2 = cL * 2 * 2048, T3 = cL * 2 * 3072, T4 = cL * 2048;
  if (idx < T1) {
    int l = idx / 12288, r = idx % 12288;
    int ki = r & 7, tt = r >> 3;
    int nn = tt % 192, kq = tt / 192;
    fc2L[idx] = f2b(fc2[((size_t)(l * 64) + kq * 8 + ki) * 192 + nn]);
  } else if (idx < T1 + T2) {
    int r0 = idx - T1;
    int l = r0 / 4096, r1 = r0 % 4096;
    int k2 = r1 / 2048, r = r1 % 2048;
    int ki = r & 7, tt = r >> 3;
    int mm = tt % 32, kq = tt / 32;
    WsvL[r0] = f2b(Wsv[((size_t)((l * 64 + kq * 8 + ki) * 2) + k2) * 32 + mm]);
  } else if (idx < T1 + T2 + T3) {
    int r0 = idx - T1 - T2;
    int l = r0 / 6144, r1 = r0 % 6144;
    int k2 = r1 / 3072, r = r1 % 3072;
    int ki = r & 7, tt = r >> 3;
    int mm = tt % 96, kq = tt / 96;
    WvsL[r0] = f2b(Wvs[((size_t)((l * 32 + kq * 8 + ki) * 2) + k2) * 96 + mm]);
  } else if (idx < T1 + T2 + T3 + T4) {
    int r0 = idx - T1 - T2 - T3;
    int l = r0 / 2048, r1 = r0 % 2048;
    int kq = r1 / 512, rem = r1 % 512;
    int n = rem / 8, ki = rem & 7;
    fc1L[r0] = (kq < 2) ? f2b(fc1[l * 1024 + (kq * 8 + ki) * 64 + n]) : (u16)0;
  }
}

__global__ void k_init(const float* __restrict__ x, const float* __restrict__ Wup,
                       float* __restrict__ v, float* __restrict__ v_old,
                       float* __restrict__ xcur, int N) {
  int idx = blockIdx.x * 256 + threadIdx.x;
  if (idx >= N * 32) return;
  int n = idx >> 5, vc = idx & 31;
  float w0 = Wup[vc], w1 = Wup[32 + vc];
#pragma unroll
  for (int c = 0; c < 3; ++c) {
    float val = x[n * 6 + c] * w0 + x[n * 6 + 3 + c] * w1;
    v[idx * 3 + c] = val;
    v_old[idx * 3 + c] = val;
  }
  if (vc < 6) xcur[n * 6 + vc] = x[n * 6 + vc];
}

// ---------------- CSR build ----------------

__global__ void k_zero_i(int* __restrict__ p, int n) {
  int i = blockIdx.x * 256 + threadIdx.x;
  if (i < n) p[i] = 0;
}

__global__ void k_hist(const int* __restrict__ edst, int* __restrict__ deg, int E) {
  int e = blockIdx.x * 256 + threadIdx.x;
  if (e < E) atomicAdd(&deg[edst[e]], 1);
}

__global__ __launch_bounds__(1024) void k_scan(const int* __restrict__ deg,
                                               int* __restrict__ row_ptr,
                                               int* __restrict__ cursor, int N) {
  __shared__ int part[1024];
  int t = threadIdx.x;
  int chunk = (N + 1023) / 1024;
  int base = t * chunk;
  int sum = 0;
  for (int i = 0; i < chunk; ++i) {
    int idx = base + i;
    if (idx < N) sum += deg[idx];
  }
  part[t] = sum;
  __syncthreads();
  for (int off = 1; off < 1024; off <<= 1) {
    int val = (t >= off) ? part[t - off] : 0;
    __syncthreads();
    part[t] += val;
    __syncthreads();
  }
  int run = (t > 0) ? part[t - 1] : 0;
  for (int i = 0; i < chunk; ++i) {
    int idx = base + i;
    if (idx < N) {
      row_ptr[idx] = run;
      cursor[idx] = run;
      run += deg[idx];
    }
  }
  if (t == 1023) row_ptr[N] = part[1023];
}

__global__ void k_scatter(const int* __restrict__ esrc, const int* __restrict__ edst,
                          int* __restrict__ cursor, int* __restrict__ esrc_s,
                          int* __restrict__ edst_s, int E) {
  int e = blockIdx.x * 256 + threadIdx.x;
  if (e < E) {
    int d = edst[e];
    int p = atomicAdd(&cursor[d], 1);
    esrc_s[p] = esrc[e];
    edst_s[p] = d;
  }
}

// ---------------- fused MFMA edge kernel: wave = 16 consecutive CSR-sorted edges ----
// msg row (bf16): SZERO stride 96: [0..95] msg_s; else stride 192: + msg_v at 96+c*32+m'
// wb 200-stride region uses XOR bank-swizzle xm200(row) on the column index.
template <bool SZERO>
__global__ __launch_bounds__(256) void k_edge_mfma(
    const float* __restrict__ xcur, const float* __restrict__ s, const float* __restrict__ v,
    const int* __restrict__ esrc_s, const int* __restrict__ edst_s,
    const u16* __restrict__ fc1L, const float* __restrict__ b1,
    const u16* __restrict__ fc2L, const u16* __restrict__ WsvL0,
    const u16* __restrict__ WsvL1, const u16* __restrict__ WvsL0,
    const u16* __restrict__ WvsL1, u16* __restrict__ msgbuf, int E) {
  __shared__ u16 wbAll[4][16 * 200];
  __shared__ float aAll[4][16][6];
  int wid = threadIdx.x >> 6, lane = threadIdx.x & 63;
  int e0 = (blockIdx.x * 4 + wid) * 16;
  if (e0 >= E) return;
  u16* wb = wbAll[wid];
  int lrow = lane & 15, lg = lane >> 4;

  int prow = e0 + lrow;
  if (prow >= E) prow = E - 1;
  int src = esrc_s[prow];   // issued first: s/v gathers depend on it

  // ====== geometry (4 lanes per edge, duplicated; qq==0 lane writes results) ======
  {
    int el = lane >> 2, qq = lane & 3;
    int ge = e0 + el;
    if (ge >= E) ge = E - 1;
    int gs = esrc_s[ge], gd = edst_s[ge];
    float xs[6], xd[6];
    {
      const float2* ps = (const float2*)(xcur + (size_t)gs * 6);
      const float2* pd = (const float2*)(xcur + (size_t)gd * 6);
      float2 A0 = ps[0], A1 = ps[1], A2 = ps[2];
      float2 B0 = pd[0], B1 = pd[1], B2 = pd[2];
      xs[0] = A0.x; xs[1] = A0.y; xs[2] = A1.x; xs[3] = A1.y; xs[4] = A2.x; xs[5] = A2.y;
      xd[0] = B0.x; xd[1] = B0.y; xd[2] = B1.x; xd[3] = B1.y; xd[4] = B2.x; xd[5] = B2.y;
    }
    float f[16], av[6];
#pragma unroll
    for (int i = 0; i < 2; ++i) {
      float vx = xs[3 * i + 0] - xd[3 * i + 0];
      float vy = xs[3 * i + 1] - xd[3 * i + 1];
      float vz = xs[3 * i + 2] - xd[3 * i + 2];
      float r2 = vx * vx + vy * vy + vz * vz;
      float rr = sqrtf(r2);
      float invr = 1.0f / rr;
      float th = (PI_F / 3.0f) * rr;
      float s1, c1;
      __sincosf(th, &s1, &c1);
      float twc = 2.0f * c1;
      float snm = 0.f, sn = s1;
      float fc = BESSEL_C * invr;
#pragma unroll
      for (int nn = 0; nn < 8; ++nn) {
        f[8 * i + nn] = fc * sn;
        float nx = twc * sn - snm;
        snm = sn;
        sn = nx;
      }
      float uu = (2.0f / 3.0f) * rr - 2.0f;
      float cut;
      if (uu > 0.f) cut = 0.f;
      else if (uu < -1.f) cut = 1.f;
      else cut = (1.0f - __cosf(PI_F * uu)) * 0.5f;
      float sc = cut * SQRT3 * invr;
      av[3 * i + 0] = vx * sc; av[3 * i + 1] = vy * sc; av[3 * i + 2] = vz * sc;
    }
    if (qq == 0) {
      // f region: stride 40 u16 (20 dwords) -> ~2-way banks, 16B-aligned rows
      u32* fp = (u32*)(wb + 1600 + el * 40);
#pragma unroll
      for (int i = 0; i < 8; ++i) fp[i] = pkbf(f[2 * i], f[2 * i + 1]);
#pragma unroll
      for (int i = 8; i < 16; ++i) fp[i] = 0u;
      float* ap = aAll[wid][el];
#pragma unroll
      for (int i = 0; i < 6; ++i) ap[i] = av[i];
    }
  }

  // ====== hoisted source-row gathers (latency hides under MLP + GEMM2) ======
  float sv0[8], sv1[8], vl[24];
  if (!SZERO) {
    const float* sp = s + (size_t)src * 64;
    *(f32x4*)(sv0) = *(const f32x4*)(sp + lg * 8);
    *(f32x4*)(sv0 + 4) = *(const f32x4*)(sp + lg * 8 + 4);
    *(f32x4*)(sv1) = *(const f32x4*)(sp + 32 + lg * 8);
    *(f32x4*)(sv1 + 4) = *(const f32x4*)(sp + 32 + lg * 8 + 4);
  }
  {
    const float* vp = v + (size_t)src * 96 + lg * 24;
#pragma unroll
    for (int i = 0; i < 6; ++i) *(f32x4*)(vl + 4 * i) = *(const f32x4*)(vp + 4 * i);
  }

  asm volatile("s_waitcnt lgkmcnt(0)" ::: "memory");
  __builtin_amdgcn_sched_barrier(0);

  // ====== MLP: hid[16][64] = silu(f @ fc1 + b1) via 4 MFMA ======
  {
    bf16x8 fA = *(const bf16x8*)(wb + 1600 + lrow * 40 + lg * 8);
    f32x4 hp[4];
#pragma unroll
    for (int nb = 0; nb < 4; ++nb) {
      bf16x8 bB = *(const bf16x8*)(fc1L + (size_t)(lg * 64 + nb * 16 + lrow) * 8);
      f32x4 z = {0.f, 0.f, 0.f, 0.f};
      hp[nb] = mfma16(fA, bB, z);
    }
#pragma unroll
    for (int nb = 0; nb < 4; ++nb) {
      float bias = b1[nb * 16 + lrow];
      float hv[4];
#pragma unroll
      for (int r = 0; r < 4; ++r) {
        float xv = hp[nb][r] + bias;
        hv[r] = xv * (1.0f / (1.0f + __expf(-xv)));
      }
      u32 p01 = pkbf(hv[0], hv[1]);
      u32 p23 = pkbf(hv[2], hv[3]);
      int col = nb * 16 + lrow;
      wb[(4 * lg + 0) * 72 + col] = (u16)p01;
      wb[(4 * lg + 1) * 72 + col] = (u16)(p01 >> 16);
      wb[(4 * lg + 2) * 72 + col] = (u16)p23;
      wb[(4 * lg + 3) * 72 + col] = (u16)(p23 >> 16);
    }
  }
  asm volatile("s_waitcnt lgkmcnt(0)" ::: "memory");
  __builtin_amdgcn_sched_barrier(0);

  // hid A-fragments
  bf16x8 ha = *(const bf16x8*)(wb + lrow * 72 + lg * 8);
  bf16x8 hbf = *(const bf16x8*)(wb + lrow * 72 + 32 + lg * 8);
  asm volatile("s_waitcnt lgkmcnt(0)" ::: "memory");   // reads done before wb overwrite

  // ---- GEMM2: w[16,192] = hid[16,64] @ fc2[64,192], store bf16 to LDS (swizzled)
  int xw = lg << 3;   // xm200 for rows 4lg..4lg+3
#pragma unroll
  for (int nb = (SZERO ? 8 : 0); nb < 12; ++nb) {
    bf16x8 b0 = *(const bf16x8*)(fc2L + (size_t)(lg * 192 + nb * 16 + lrow) * 8);
    bf16x8 b1v = *(const bf16x8*)(fc2L + (size_t)((4 + lg) * 192 + nb * 16 + lrow) * 8);
    f32x4 c = {0.f, 0.f, 0.f, 0.f};
    c = mfma16(ha, b0, c);
    c = mfma16(hbf, b1v, c);
    int n = nb * 16 + lrow;
    int pn = (n < 128) ? ((n & 1) * 64 + (n >> 1)) : (128 + (n & 1) * 32 + ((n - 128) >> 1));
    int rbase = 4 * lg * 200 + (pn ^ xw);
    u32 p01 = pkbf(c[0], c[1]);
    u32 p23 = pkbf(c[2], c[3]);
    wb[rbase] = (u16)p01;
    wb[rbase + 200] = (u16)(p01 >> 16);
    wb[rbase + 400] = (u16)p23;
    wb[rbase + 600] = (u16)(p23 >> 16);
  }
  asm volatile("s_waitcnt lgkmcnt(0)" ::: "memory");

  // swizzled row pointer for this lane's w-row (offsets used are multiples of 32)
  const u16* wrow = wb + lrow * 200 + (((lg ^ (lrow >> 2)) & 3) << 3);

  // ---- Q path: T_k = s_src (.) w1_k ; Q_k = T_k @ W_sv_k
  f32x4 q0[2], q1[2];
  if (!SZERO) {
    i32x4 W0a = *(const i32x4*)(wrow);
    i32x4 W0b = *(const i32x4*)(wrow + 32);
    i32x4 W1a = *(const i32x4*)(wrow + 64);
    i32x4 W1b = *(const i32x4*)(wrow + 96);
    U8 t0a, t0b, t1a, t1b;
#pragma unroll
    for (int j2 = 0; j2 < 4; ++j2) {
      u32 wa = (u32)W0a[j2], wbv = (u32)W0b[j2], wc = (u32)W1a[j2], wd = (u32)W1b[j2];
      t0a.w[j2] = pkbf(sv0[2 * j2] * blo(wa), sv0[2 * j2 + 1] * bhi(wa));
      t0b.w[j2] = pkbf(sv1[2 * j2] * blo(wbv), sv1[2 * j2 + 1] * bhi(wbv));
      t1a.w[j2] = pkbf(sv0[2 * j2] * blo(wc), sv0[2 * j2 + 1] * bhi(wc));
      t1b.w[j2] = pkbf(sv1[2 * j2] * blo(wd), sv1[2 * j2 + 1] * bhi(wd));
    }
#pragma unroll
    for (int nb = 0; nb < 2; ++nb) {
      bf16x8 bA = *(const bf16x8*)(WsvL0 + (size_t)(lg * 32 + nb * 16 + lrow) * 8);
      bf16x8 bB = *(const bf16x8*)(WsvL0 + (size_t)((4 + lg) * 32 + nb * 16 + lrow) * 8);
      f32x4 c = {0.f, 0.f, 0.f, 0.f};
      c = mfma16(t0a.v, bA, c);
      c = mfma16(t0b.v, bB, c);
      q0[nb] = c;
      bf16x8 bC = *(const bf16x8*)(WsvL1 + (size_t)(lg * 32 + nb * 16 + lrow) * 8);
      bf16x8 bD = *(const bf16x8*)(WsvL1 + (size_t)((4 + lg) * 32 + nb * 16 + lrow) * 8);
      f32x4 c2 = {0.f, 0.f, 0.f, 0.f};
      c2 = mfma16(t1a.v, bC, c2);
      c2 = mfma16(t1b.v, bD, c2);
      q1[nb] = c2;
    }
  }

  // ---- M path: G_k = (v_src . a_k) (.) w2_k ; msg_s = G_0 @ Wvs_0 + G_1 @ Wvs_1
  float a00, a01, a02, a10, a11, a12;
  {
    const float* ap = aAll[wid][lrow];
    a00 = ap[0]; a01 = ap[1]; a02 = ap[2]; a10 = ap[3]; a11 = ap[4]; a12 = ap[5];
  }
  i32x4 W2a = *(const i32x4*)(wrow + 128);
  i32x4 W2b = *(const i32x4*)(wrow + 160);
  U8 ga, gb;
#pragma unroll
  for (int j2 = 0; j2 < 4; ++j2) {
    float d0a, d1a, d0b, d1b;
    {
      float vx = vl[6 * j2 + 0], vy = vl[6 * j2 + 1], vz = vl[6 * j2 + 2];
      d0a = vx * a00 + vy * a01 + vz * a02;
      d1a = vx * a10 + vy * a11 + vz * a12;
    }
    {
      float vx = vl[6 * j2 + 3], vy = vl[6 * j2 + 4], vz = vl[6 * j2 + 5];
      d0b = vx * a00 + vy * a01 + vz * a02;
      d1b = vx * a10 + vy * a11 + vz * a12;
    }
    u32 wa = (u32)W2a[j2], wbv = (u32)W2b[j2];
    ga.w[j2] = pkbf(d0a * blo(wa), d0b * bhi(wa));
    gb.w[j2] = pkbf(d1a * blo(wbv), d1b * bhi(wbv));
  }
  f32x4 mS[6];
#pragma unroll
  for (int nb = 0; nb < 6; ++nb) {
    bf16x8 b0 = *(const bf16x8*)(WvsL0 + (size_t)(lg * 96 + nb * 16 + lrow) * 8);
    bf16x8 b1v = *(const bf16x8*)(WvsL1 + (size_t)(lg * 96 + nb * 16 + lrow) * 8);
    f32x4 c = {0.f, 0.f, 0.f, 0.f};
    c = mfma16(ga.v, b0, c);
    c = mfma16(gb.v, b1v, c);
    mS[nb] = c;
  }

  // ---- stage final msg rows into wb (overwrite w; swizzled)
  asm volatile("s_waitcnt lgkmcnt(0)" ::: "memory");
#pragma unroll
  for (int nb = 0; nb < 6; ++nb) {
    u32 p01 = pkbf(mS[nb][0], mS[nb][1]);
    u32 p23 = pkbf(mS[nb][2], mS[nb][3]);
    int colx = (nb * 16 + lrow) ^ xw;
    wb[(4 * lg + 0) * 200 + colx] = (u16)p01;
    wb[(4 * lg + 1) * 200 + colx] = (u16)(p01 >> 16);
    wb[(4 * lg + 2) * 200 + colx] = (u16)p23;
    wb[(4 * lg + 3) * 200 + colx] = (u16)(p23 >> 16);
  }
  if (!SZERO) {
#pragma unroll
    for (int nb = 0; nb < 2; ++nb) {
#pragma unroll
      for (int r = 0; r < 4; ++r) {
        int el = 4 * lg + r;
        const float* ap = aAll[wid][el];
        float Q0v = q0[nb][r], Q1v = q1[nb][r];
        float v0 = Q0v * ap[0] + Q1v * ap[3];
        float v1 = Q0v * ap[1] + Q1v * ap[4];
        float v2 = Q0v * ap[2] + Q1v * ap[5];
        u32 p01 = pkbf(v0, v1);
        int base = el * 200 + ((96 + nb * 16 + lrow) ^ xw);
        wb[base] = (u16)p01;
        wb[base + 32] = (u16)(p01 >> 16);
        wb[base + 64] = f2b(v2);
      }
    }
  }
  asm volatile("s_waitcnt lgkmcnt(0)" ::: "memory");

  // ---- cooperative coalesced write: 16 consecutive rows, stride 96 (SZERO) / 192
  int orow = lane >> 2, oq = lane & 3;
  if (e0 + orow < E) {
    const int OST = SZERO ? 96 : 192;
    u16* gdst = msgbuf + (size_t)(e0 + orow) * OST;
    int xo = ((orow >> 2) & 3) << 3;
    const int NIT = SZERO ? 3 : 6;
#pragma unroll
    for (int it = 0; it < NIT; ++it) {
      int col = oq * 8 + it * 32;
      i32x4 d = *(const i32x4*)(wb + orow * 200 + (col ^ xo));
      *(i32x4*)(gdst + col) = d;
    }
  }
}

// ---------------- fused gather + node update (2 nodes per 256-thread block) --------
template <bool SZERO>
__global__ __launch_bounds__(256) void k_gnode(
    const u16* __restrict__ msg, const int* __restrict__ row_ptr,
    float* __restrict__ s, float* __restrict__ sold, float* __restrict__ v,
    float* __restrict__ vold,
    const float* __restrict__ Amat, const float* __restrict__ Bmat,
    const float* __restrict__ Ws, const float* __restrict__ Wv,
    const float* __restrict__ Wproj, const int* __restrict__ nattr,
    const float* __restrict__ hArr, const float* __restrict__ mixArr, int layer,
    float* __restrict__ xout, int N) {
  int half = threadIdx.x >> 7;
  int t = threadIdx.x & 127;
  int n = blockIdx.x * 2 + half;
  bool active = n < N;
  if (!active) n = N - 1;
  __shared__ float agg[2][192];
  __shared__ float srow[2][64];
  __shared__ float vrow[2][96];
  __shared__ float gateS[2][32];
  __shared__ float vnewS[2][96];
  int start = row_ptr[n], end = row_ptr[n + 1];
  const int STRIDE = SZERO ? 96 : 192;
  int nacc = SZERO ? 48 : 96;
  if (t < nacc) {
    const u16* mp = msg + (size_t)t * 2;
    float aL[4] = {0.f, 0.f, 0.f, 0.f}, aH[4] = {0.f, 0.f, 0.f, 0.f};
    int p = start;
    for (; p + 8 <= end; p += 8) {
      u32 w[8];
#pragma unroll
      for (int k = 0; k < 8; ++k) w[k] = *(const u32*)(mp + (size_t)(p + k) * STRIDE);
#pragma unroll
      for (int k = 0; k < 8; ++k) {
        aL[k & 3] += blo(w[k]);
        aH[k & 3] += bhi(w[k]);
      }
    }
    for (; p < end; ++p) {
      u32 w = *(const u32*)(mp + (size_t)p * STRIDE);
      aL[0] += blo(w);
      aH[0] += bhi(w);
    }
    agg[half][2 * t] = (aL[0] + aL[1] + aL[2] + aL[3]) * INV_SQRT_NN;
    agg[half][2 * t + 1] = (aH[0] + aH[1] + aH[2] + aH[3]) * INV_SQRT_NN;
  }
  if (SZERO && t >= 48 && t < 96) {
    agg[half][2 * t] = 0.f;
    agg[half][2 * t + 1] = 0.f;
  }
  if (t < 64) srow[half][t] = s[(size_t)n * 64 + t];
  if (t < 96) vrow[half][t] = v[(size_t)n * 96 + t];
  __syncthreads();
  int type = nattr[n];
  float hv = hArr[layer];
  float h2v = hv * hv;
  float mx = mixArr[layer];
  float cs = 0.f;
  if (t < 96) {
    cs = agg[half][t];
    const float* Ac = Amat + (size_t)type * 64 * 96 + t;
#pragma unroll 8
    for (int u = 0; u < 64; ++u) cs += srow[half][u] * Ac[u * 96];
  }
  if (t >= 64 && t < 96) gateS[half][t - 64] = 1.0f / (1.0f + __expf(-cs));
  __syncthreads();
  if (t < 64) {
    float gs = cs * (1.0f / (1.0f + __expf(-cs)));
    float sis = 0.f;
#pragma unroll 8
    for (int u = 0; u < 64; ++u) sis += srow[half][u] * Ws[u * 64 + t];
    float scur = srow[half][t];
    float sprev = sold[(size_t)n * 64 + t];
    float snew = 2.f * scur - sprev + h2v * (mx * gs + (mx - 1.f) * sis);
    if (active) {
      sold[(size_t)n * 64 + t] = scur;
      s[(size_t)n * 64 + t] = snew;
    }
  }
  if (t < 96) {
    int vch = t / 3, c = t - vch * 3;
    float cv = agg[half][96 + c * 32 + vch];
    const float* Bc = Bmat + (size_t)type * 1024 + vch;
    float scv = 0.f, siv = 0.f;
#pragma unroll 8
    for (int u = 0; u < 32; ++u) {
      float vu = vrow[half][u * 3 + c];
      scv += vu * Bc[u * 32];
      siv += vu * Wv[u * 32 + vch];
    }
    cv += scv;
    float gv = cv * gateS[half][vch];
    float vcur = vrow[half][t];
    float vprev = vold[(size_t)n * 96 + t];
    float vnew = 2.f * vcur - vprev + h2v * (mx * gv + (mx - 1.f) * siv);
    if (active) {
      vold[(size_t)n * 96 + t] = vcur;
      v[(size_t)n * 96 + t] = vnew;
    }
    vnewS[half][t] = vnew;
  }
  __syncthreads();
  if (t < 6 && active) {
    int i = t / 3, c = t - i * 3;
    float acc = 0.f;
#pragma unroll
    for (int vo = 0; vo < 32; ++vo) acc += vnewS[half][vo * 3 + c] * Wproj[vo * 2 + i];
    xout[(size_t)n * 6 + t] = acc;
  }
}

extern "C" void kernel_launch(void* const* d_in, const int* in_sizes, int n_in,
                              void* d_out, int out_size, void* d_ws, size_t ws_size,
                              hipStream_t stream) {
  const float* x = (const float*)d_in[0];
  const float* emb = (const float*)d_in[1];
  const float* Wup = (const float*)d_in[2];
  const float* Wproj = (const float*)d_in[3];
  const float* fc1 = (const float*)d_in[4];
  const float* b1 = (const float*)d_in[5];
  const float* fc2 = (const float*)d_in[6];
  const float* Wsv = (const float*)d_in[7];
  const float* Wvs = (const float*)d_in[8];
  const float* Wscs = (const float*)d_in[9];
  const float* Wscv = (const float*)d_in[10];
  const float* Ws = (const float*)d_in[11];
  const float* Wv = (const float*)d_in[12];
  const float* hArr = (const float*)d_in[13];
  const float* mixArr = (const float*)d_in[14];
  const int* nattr = (const int*)d_in[15];
  const int* esrc = (const int*)d_in[16];
  const int* edst = (const int*)d_in[17];

  const int N = in_sizes[0] / 6;
  const int E = in_sizes[16];

  float* ws = (float*)d_ws;
  size_t off = 0;
  auto alloc = [&](size_t nf) {
    float* p = ws + off;
    off += (nf + 3) & ~(size_t)3;
    return p;
  };
  float* sbuf = alloc((size_t)N * 64);
  float* sold = alloc((size_t)N * 64);
  float* vbuf = alloc((size_t)N * 96);
  float* vold = alloc((size_t)N * 96);
  float* xcur = alloc((size_t)N * 6);
  float* Amat = alloc((size_t)cL * cNT * 64 * 96);
  float* Bmat = alloc((size_t)cL * cNT * 32 * 32);
  u16* fc2L = (u16*)alloc((size_t)cL * 6144);       // L*12288 bf16
  u16* WsvL = (u16*)alloc((size_t)cL * 2048);       // L*2*2048 bf16
  u16* WvsL = (u16*)alloc((size_t)cL * 3072);       // L*2*3072 bf16
  u16* fc1L = (u16*)alloc((size_t)cL * 1024);       // L*2048 bf16 (kq padded to 4)
  int* deg = (int*)alloc((size_t)(N + 4));
  int* row_ptr = (int*)alloc((size_t)(N + 4));
  int* cursor = (int*)alloc((size_t)(N + 4));
  int* esrc_s = (int*)alloc((size_t)E);
  int* edst_s = (int*)alloc((size_t)E);
  u16* msgbuf = (u16*)alloc((size_t)E * 96);        // E*192 bf16

  // init
  hipMemsetAsync(sbuf, 0, sizeof(float) * (size_t)N * 128, stream);  // sbuf + sold
  k_init<<<(N * 32 + 255) / 256, 256, 0, stream>>>(x, Wup, vbuf, vold, xcur, N);
  k_precompA<<<(cL * cNT * 64 * 96 + 255) / 256, 256, 0, stream>>>(emb, Wscs, Amat);
  k_precompB<<<(cL * cNT * 32 * 32 + 255) / 256, 256, 0, stream>>>(emb, Wscv, Bmat);
  {
    int tot = cL * 12288 + cL * 4096 + cL * 6144 + cL * 2048;
    k_packB<<<(tot + 255) / 256, 256, 0, stream>>>(fc2, Wsv, Wvs, fc1, fc2L, WsvL, WvsL, fc1L);
  }
  k_zero_i<<<(N + 255) / 256, 256, 0, stream>>>(deg, N);
  k_hist<<<(E + 255) / 256, 256, 0, stream>>>(edst, deg, E);
  k_scan<<<1, 1024, 0, stream>>>(deg, row_ptr, cursor, N);
  k_scatter<<<(E + 255) / 256, 256, 0, stream>>>(esrc, edst, cursor, esrc_s, edst_s, E);

  int eblocks = ((E + 15) / 16 + 3) / 4;
  int gblocks = (N + 1) / 2;
  for (int l = 0; l < cL; ++l) {
    if (l == 0)
      k_edge_mfma<true><<<eblocks, 256, 0, stream>>>(
          xcur, sbuf, vbuf, esrc_s, edst_s, fc1L + l * 2048, b1 + l * 64,
          fc2L + l * 12288, WsvL + l * 4096, WsvL + l * 4096 + 2048,
          WvsL + l * 6144, WvsL + l * 6144 + 3072, msgbuf, E);
    else
      k_edge_mfma<false><<<eblocks, 256, 0, stream>>>(
          xcur, sbuf, vbuf, esrc_s, edst_s, fc1L + l * 2048, b1 + l * 64,
          fc2L + l * 12288, WsvL + l * 4096, WsvL + l * 4096 + 2048,
          WvsL + l * 6144, WvsL + l * 6144 + 3072, msgbuf, E);
    float* xout = (l == cL - 1) ? (float*)d_out : xcur;
    if (l == 0)
      k_gnode<true><<<gblocks, 256, 0, stream>>>(
          msgbuf, row_ptr, sbuf, sold, vbuf, vold, Amat + (size_t)l * cNT * 64 * 96,
          Bmat + (size_t)l * cNT * 1024, Ws + l * 4096, Wv + l * 1024, Wproj, nattr,
          hArr, mixArr, l, xout, N);
    else
      k_gnode<false><<<gblocks, 256, 0, stream>>>(
          msgbuf, row_ptr, sbuf, sold, vbuf, vold, Amat + (size_t)l * cNT * 64 * 96,
          Bmat + (size_t)l * cNT * 1024, Ws + l * 4096, Wv + l * 1024, Wproj, nattr,
          hArr, mixArr, l, xout, N);
  }
}